// Round 1
// baseline (841.248 us; speedup 1.0000x reference)
//
#include <hip/hip_runtime.h>
#include <hip/hip_bf16.h>
#include <cstdint>
#include <cstddef>

// Problem: B=4, S=4096, D=256 two-layer full attention + VAE head. fp32 I/O.
// Strategy: bf16 MFMA everywhere GEMM-shaped; fp32 softmax/epilogue.

#define S_LEN 4096
#define DMODEL 256
#define NBATCH 4
#define MTOT (NBATCH * S_LEN)  // 16384

typedef __bf16 bf16;
typedef __bf16 bf16x8 __attribute__((ext_vector_type(8)));
typedef float f32x4 __attribute__((ext_vector_type(4)));

__device__ __forceinline__ f32x4 mfma16(bf16x8 a, bf16x8 b, f32x4 c) {
  return __builtin_amdgcn_mfma_f32_16x16x32_bf16(a, b, c, 0, 0, 0);
}

// Async global->LDS, 16B per lane. LDS dest semantics: wave-uniform base + lane*16.
__device__ __forceinline__ void async16(bf16* lds, const bf16* g) {
  __builtin_amdgcn_global_load_lds(
      (const __attribute__((address_space(1))) unsigned int*)g,
      (__attribute__((address_space(3))) unsigned int*)lds, 16, 0, 0);
}

__device__ __forceinline__ unsigned short f2bfbits(float f) {
  return __builtin_bit_cast(unsigned short, (bf16)f);
}

// ---------------- cast kernels ----------------
__global__ void cast_x_kernel(const f32x4* __restrict__ src, ushort4* __restrict__ dst, int n4) {
  int i = blockIdx.x * 256 + threadIdx.x;
  if (i >= n4) return;
  f32x4 v = src[i];
  ushort4 o;
  o.x = f2bfbits(v[0]); o.y = f2bfbits(v[1]); o.z = f2bfbits(v[2]); o.w = f2bfbits(v[3]);
  dst[i] = o;
}

struct WPtrs { const float* p[8]; };

__global__ void cast_w_kernel(WPtrs wp, ushort4* __restrict__ dst) {
  int m = blockIdx.y;
  const f32x4* s = (const f32x4*)wp.p[m];
  int i = blockIdx.x * 256 + threadIdx.x;  // 0..16383
  f32x4 v = s[i];
  ushort4 o;
  o.x = f2bfbits(v[0]); o.y = f2bfbits(v[1]); o.z = f2bfbits(v[2]); o.w = f2bfbits(v[3]);
  dst[(size_t)m * 16384 + i] = o;
}

// ---------------- GEMM: out[m][n] = sum_k A[m][k]*W[n][k] + bias[n] ----------------
// A: [MTOT][256] bf16 row-major; W: [256][256] bf16 row-major (out-feature major).
// 128x128 tile, BK=64, 4 waves (each 64x64 = 4x4 of 16x16 MFMA).
// LDS rows of 64 elems = 8x16B chunks, XOR-swizzled: chunk slot c8s holds global chunk c8s^(r&7).
struct GemmIO {
  const float* bias[3];
  void* out[3];
};

template <typename OutT>
__global__ __launch_bounds__(256, 3) void gemm_kernel(const bf16* __restrict__ A,
                                                      const bf16* __restrict__ Wb, GemmIO io) {
  __shared__ bf16 ldsA[128 * 64];
  __shared__ bf16 ldsB[128 * 64];
  const int t = threadIdx.x;
  const int m0 = blockIdx.x * 128;
  const int n0 = blockIdx.y * 128;
  const bf16* W = Wb + (size_t)blockIdx.z * 65536;
  const int w = t >> 6, l = t & 63, lm = l & 15, q = l >> 4;
  const int wr = (w >> 1) * 64, wc = (w & 1) * 64;

  f32x4 acc[4][4] = {};
#pragma unroll 1
  for (int it = 0; it < 4; ++it) {
    const int k0 = it * 64;
#pragma unroll
    for (int c = 0; c < 4; ++c) {
      int i = c * 256 + t;
      int r = i >> 3, c8 = (i & 7) ^ (r & 7);
      async16(&ldsA[i * 8], A + (size_t)(m0 + r) * 256 + k0 + c8 * 8);
    }
#pragma unroll
    for (int c = 0; c < 4; ++c) {
      int i = c * 256 + t;
      int r = i >> 3, c8 = (i & 7) ^ (r & 7);
      async16(&ldsB[i * 8], W + (size_t)(n0 + r) * 256 + k0 + c8 * 8);
    }
    __syncthreads();
#pragma unroll
    for (int ks = 0; ks < 2; ++ks) {
      bf16x8 af[4], bfr[4];
#pragma unroll
      for (int i = 0; i < 4; ++i) {
        int ra = wr + i * 16 + lm;
        af[i] = *(const bf16x8*)&ldsA[ra * 64 + ((((ks << 2) + q) ^ (ra & 7)) << 3)];
        int rb = wc + i * 16 + lm;
        bfr[i] = *(const bf16x8*)&ldsB[rb * 64 + ((((ks << 2) + q) ^ (rb & 7)) << 3)];
      }
#pragma unroll
      for (int i = 0; i < 4; ++i)
#pragma unroll
        for (int jj = 0; jj < 4; ++jj) acc[i][jj] = mfma16(af[i], bfr[jj], acc[i][jj]);
    }
    __syncthreads();
  }
  const float* bias = io.bias[blockIdx.z];
  OutT* out = (OutT*)io.out[blockIdx.z];
#pragma unroll
  for (int jj = 0; jj < 4; ++jj) {
    int col = n0 + wc + jj * 16 + lm;
    float bv = bias[col];
#pragma unroll
    for (int i = 0; i < 4; ++i) {
      int row = m0 + wr + i * 16 + q * 4;
#pragma unroll
      for (int r = 0; r < 4; ++r)
        out[(size_t)(row + r) * 256 + col] = (OutT)(acc[i][jj][r] + bv);
    }
  }
}

// ---------------- transpose: V [B][S][256] -> Vt [B][256][S] ----------------
__global__ void transpose_kernel(const bf16* __restrict__ src, bf16* __restrict__ dst) {
  __shared__ bf16 tile[64][72];
  int s0 = blockIdx.x * 64, d0 = blockIdx.y * 64;
  size_t boff = (size_t)blockIdx.z * S_LEN * 256;
  size_t boffT = (size_t)blockIdx.z * 256 * S_LEN;
  int t = threadIdx.x;
#pragma unroll
  for (int rep = 0; rep < 16; ++rep) {
    int lin = rep * 256 + t;
    int r = lin >> 6, c = lin & 63;
    tile[r][c] = src[boff + (size_t)(s0 + r) * 256 + d0 + c];
  }
  __syncthreads();
#pragma unroll
  for (int rep = 0; rep < 16; ++rep) {
    int lin = rep * 256 + t;
    int r = lin >> 6, c = lin & 63;
    dst[boffT + (size_t)(d0 + r) * S_LEN + s0 + c] = tile[c][r];
  }
}

// ---------------- flash attention ----------------
// Grid 256 blocks (1/CU), 4 waves. BM=64 Q rows/block (16/wave), KV tiles of 64.
// K tile LDS rows = 256 elems = 32 chunks, swizzle c8s = c8 ^ (n&31).
// Vt tile LDS rows = 64 elems = 8 chunks, swizzle c8 ^ (d&7).
__device__ __forceinline__ void stage_kv(const bf16* __restrict__ Kb, const bf16* __restrict__ Vb,
                                         bf16* dK, bf16* dV, int kv0, int t) {
#pragma unroll
  for (int c = 0; c < 8; ++c) {
    int i = c * 256 + t;
    int n = i >> 5;
    int c8 = (i & 31) ^ (n & 31);
    async16(dK + i * 8, Kb + ((size_t)(kv0 + n) << 8) + (c8 << 3));
  }
#pragma unroll
  for (int c = 0; c < 8; ++c) {
    int i = c * 256 + t;
    int d = i >> 3;
    int c8 = (i & 7) ^ (d & 7);
    async16(dV + i * 8, Vb + (size_t)d * S_LEN + kv0 + (c8 << 3));
  }
}

__global__ __launch_bounds__(256, 1) void flash_kernel(const bf16* __restrict__ Q,
                                                       const bf16* __restrict__ K,
                                                       const bf16* __restrict__ Vt,
                                                       bf16* __restrict__ O) {
  __shared__ bf16 ldsK[2][64 * 256];   // 2 x 32KB
  __shared__ bf16 ldsV[2][256 * 64];   // 2 x 32KB
  __shared__ bf16 ldsP[4][16 * 80];    // 10KB, padded rows (160B, 16B-aligned)

  const int id = blockIdx.x;
  // XCD-aware swizzle: batch b pinned to XCDs {2b,2b+1} so K+V (4MB) stays L2-resident.
  const int xcd = id & 7;
  const int b = xcd >> 1;
  const int qt = (id >> 3) + ((xcd & 1) << 5);  // 0..63

  const bf16* Qb = Q + (size_t)b * S_LEN * 256;
  const bf16* Kb = K + (size_t)b * S_LEN * 256;
  const bf16* Vb = Vt + (size_t)b * 256 * S_LEN;
  bf16* Ob = O + (size_t)b * S_LEN * 256;

  const int t = threadIdx.x, w = t >> 6, l = t & 63, lm = l & 15, q = l >> 4;
  const float CL2 = 0.09016844005556021f;  // log2(e)/sqrt(D)=log2(e)/16

  // Q fragments persistent in registers: rows qt*64 + w*16 + lm, all 256 k.
  bf16x8 qf[8];
  {
    const bf16* qrow = Qb + (size_t)(qt * 64 + w * 16 + lm) * 256;
#pragma unroll
    for (int ks = 0; ks < 8; ++ks) qf[ks] = *(const bf16x8*)(qrow + ks * 32 + q * 8);
  }

  f32x4 o_acc[16] = {};
  float m_r[4] = {-INFINITY, -INFINITY, -INFINITY, -INFINITY};
  float l_r[4] = {0.f, 0.f, 0.f, 0.f};

  stage_kv(Kb, Vb, &ldsK[0][0], &ldsV[0][0], 0, t);

#pragma unroll 1
  for (int j = 0; j < 64; ++j) {
    const int cur = j & 1;
    __syncthreads();  // stage(j) complete (vmcnt drained); compute(j-1) done everywhere
    if (j + 1 < 64) stage_kv(Kb, Vb, &ldsK[cur ^ 1][0], &ldsV[cur ^ 1][0], (j + 1) * 64, t);

    // S = Q K^T (raw scores)
    f32x4 sv[4];
#pragma unroll
    for (int jt = 0; jt < 4; ++jt) {
      f32x4 s = {0.f, 0.f, 0.f, 0.f};
      const int n = jt * 16 + lm;
      const bf16* kr = &ldsK[cur][n * 256];
#pragma unroll
      for (int ks = 0; ks < 8; ++ks) {
        bf16x8 kf = *(const bf16x8*)(kr + ((((ks << 2) + q) ^ (n & 31)) << 3));
        s = mfma16(qf[ks], kf, s);
      }
      sv[jt] = s;
    }

    // online softmax (row r lives in reg r; cols spread over 16 lanes x 4 jt tiles)
    float mnew[4], alpha[4], rs[4];
#pragma unroll
    for (int r = 0; r < 4; ++r) {
      float mx = fmaxf(fmaxf(sv[0][r], sv[1][r]), fmaxf(sv[2][r], sv[3][r]));
      mx = fmaxf(mx, __shfl_xor(mx, 1, 64));
      mx = fmaxf(mx, __shfl_xor(mx, 2, 64));
      mx = fmaxf(mx, __shfl_xor(mx, 4, 64));
      mx = fmaxf(mx, __shfl_xor(mx, 8, 64));
      mnew[r] = fmaxf(m_r[r], mx);
      alpha[r] = exp2f((m_r[r] - mnew[r]) * CL2);
      m_r[r] = mnew[r];
      rs[r] = 0.f;
    }
#pragma unroll
    for (int jt = 0; jt < 4; ++jt)
#pragma unroll
      for (int r = 0; r < 4; ++r) {
        float p = exp2f((sv[jt][r] - mnew[r]) * CL2);
        sv[jt][r] = p;
        rs[r] += p;
      }
#pragma unroll
    for (int r = 0; r < 4; ++r) {
      float acc = rs[r];
      acc += __shfl_xor(acc, 1, 64);
      acc += __shfl_xor(acc, 2, 64);
      acc += __shfl_xor(acc, 4, 64);
      acc += __shfl_xor(acc, 8, 64);
      l_r[r] = l_r[r] * alpha[r] + acc;
    }
#pragma unroll
    for (int nt = 0; nt < 16; ++nt)
#pragma unroll
      for (int r = 0; r < 4; ++r) o_acc[nt][r] *= alpha[r];

    // P: C-layout -> LDS -> A-layout (per-wave private strip, no barrier needed)
#pragma unroll
    for (int jt = 0; jt < 4; ++jt)
#pragma unroll
      for (int r = 0; r < 4; ++r)
        ldsP[w][(q * 4 + r) * 80 + jt * 16 + lm] = (bf16)sv[jt][r];
    bf16x8 pa[2];
#pragma unroll
    for (int k2 = 0; k2 < 2; ++k2)
      pa[k2] = *(const bf16x8*)&ldsP[w][lm * 80 + k2 * 32 + q * 8];

    // O += P @ V  (B-operand from Vt rows: contiguous 16B, swizzled)
#pragma unroll
    for (int nt = 0; nt < 16; ++nt) {
      const int dd = nt * 16 + lm;
      const bf16* vr = &ldsV[cur][dd * 64];
#pragma unroll
      for (int k2 = 0; k2 < 2; ++k2) {
        bf16x8 vf = *(const bf16x8*)(vr + ((((k2 << 2) + q) ^ (dd & 7)) << 3));
        o_acc[nt] = mfma16(pa[k2], vf, o_acc[nt]);
      }
    }
  }

  float inv_l[4];
#pragma unroll
  for (int r = 0; r < 4; ++r) inv_l[r] = 1.0f / l_r[r];
  bf16* orow = Ob + (size_t)(qt * 64 + w * 16) * 256;
#pragma unroll
  for (int nt = 0; nt < 16; ++nt)
#pragma unroll
    for (int r = 0; r < 4; ++r)
      orow[(size_t)(q * 4 + r) * 256 + nt * 16 + lm] = (bf16)(o_acc[nt][r] * inv_l[r]);
}

// ---------------- gate ----------------
__global__ void gate_reduce(const bf16* __restrict__ h, float* __restrict__ hbar) {
  int bb = blockIdx.y, d0 = blockIdx.x * 64;
  int t = threadIdx.x;
  int dd = d0 + (t & 63), sg = t >> 6;
  const bf16* hb = h + (size_t)bb * S_LEN * 256;
  float acc = 0.f;
  for (int s = sg; s < S_LEN; s += 4) acc += (float)hb[(size_t)s * 256 + dd];
  __shared__ float red[256];
  red[t] = acc;
  __syncthreads();
  if (t < 64)
    hbar[bb * 256 + dd] = (red[t] + red[t + 64] + red[t + 128] + red[t + 192]) * (1.0f / 4096.0f);
}

__global__ void gate_final(const float* __restrict__ hbar, const float* __restrict__ Wg,
                           const float* __restrict__ bg, float* __restrict__ pg) {
  int t = threadIdx.x;
  int bb = t >> 6, l = t & 63;
  float a = 0.f;
  for (int d = l; d < 256; d += 64) a += hbar[bb * 256 + d] * Wg[d];
#pragma unroll
  for (int d = 1; d < 64; d <<= 1) a += __shfl_xor(a, d, 64);
  if (l == 0) pg[bb] = 1.0f / (1.0f + __expf(-(a + bg[0])));
}

// ---------------- fused reparam + ELU + residual + LayerNorm ----------------
__global__ __launch_bounds__(64) void epilogue_kernel(const float* __restrict__ x,
                                                      const float* __restrict__ eps,
                                                      const float* __restrict__ mu,
                                                      const float* __restrict__ lv,
                                                      const float* __restrict__ gamma,
                                                      const float* __restrict__ beta,
                                                      float* __restrict__ out) {
  size_t base = (size_t)blockIdx.x * 256;
  int l = threadIdx.x;
  f32x4 xv = ((const f32x4*)(x + base))[l];
  f32x4 ev = ((const f32x4*)(eps + base))[l];
  f32x4 mv = ((const f32x4*)(mu + base))[l];
  f32x4 vv = ((const f32x4*)(lv + base))[l];
  f32x4 y;
  float s = 0.f, s2 = 0.f;
#pragma unroll
  for (int c = 0; c < 4; ++c) {
    float z = mv[c] + ev[c] * __expf(0.5f * vv[c]);
    z = z > 0.f ? z : (__expf(z) - 1.f);
    float yy = xv[c] + z;
    y[c] = yy;
    s += yy;
    s2 += yy * yy;
  }
#pragma unroll
  for (int d = 1; d < 64; d <<= 1) {
    s += __shfl_xor(s, d, 64);
    s2 += __shfl_xor(s2, d, 64);
  }
  float mean = s * (1.f / 256.f);
  float var = s2 * (1.f / 256.f) - mean * mean;
  float rstd = rsqrtf(var + 1e-5f);
  f32x4 gv = ((const f32x4*)gamma)[l];
  f32x4 bv = ((const f32x4*)beta)[l];
  f32x4 o;
#pragma unroll
  for (int c = 0; c < 4; ++c) o[c] = (y[c] - mean) * rstd * gv[c] + bv[c];
  ((f32x4*)(out + base))[l] = o;
}

// ---------------- launch ----------------
extern "C" void kernel_launch(void* const* d_in, const int* in_sizes, int n_in, void* d_out,
                              int out_size, void* d_ws, size_t ws_size, hipStream_t stream) {
  const float* x = (const float*)d_in[0];
  const float* eps = (const float*)d_in[1];
  const float* Wg = (const float*)d_in[18];
  const float* bg = (const float*)d_in[19];
  const float* gamma = (const float*)d_in[20];
  const float* beta = (const float*)d_in[21];

  char* ws = (char*)d_ws;
  bf16* x16 = (bf16*)(ws);                  // 8 MB
  bf16* q16 = (bf16*)(ws + 8388608);        // 8 MB
  bf16* k16 = (bf16*)(ws + 16777216);       // 8 MB
  bf16* v16 = (bf16*)(ws + 25165824);       // 8 MB
  bf16* vt16 = (bf16*)(ws + 33554432);      // 8 MB
  bf16* h16 = (bf16*)(ws + 41943040);       // 8 MB
  bf16* w16 = (bf16*)(ws + 50331648);       // 1 MB (8 x 256x256 bf16)
  float* hbar = (float*)(ws + 51380224);    // 4 KB

  float* out = (float*)d_out;
  float* mu = out + 4194304;
  float* lv = out + 8388608;
  float* pg = out + 12582912;

  cast_x_kernel<<<4096, 256, 0, stream>>>((const f32x4*)x, (ushort4*)x16, 1048576);
  WPtrs wp;
  for (int i = 0; i < 8; ++i) wp.p[i] = (const float*)d_in[2 + i];
  cast_w_kernel<<<dim3(64, 8), 256, 0, stream>>>(wp, (ushort4*)w16);

  GemmIO io1;
  io1.bias[0] = (const float*)d_in[10];
  io1.bias[1] = (const float*)d_in[11];
  io1.bias[2] = (const float*)d_in[12];
  io1.out[0] = q16; io1.out[1] = k16; io1.out[2] = v16;
  gemm_kernel<bf16><<<dim3(128, 2, 3), 256, 0, stream>>>(x16, w16, io1);
  transpose_kernel<<<dim3(64, 4, 4), 256, 0, stream>>>(v16, vt16);
  flash_kernel<<<256, 256, 0, stream>>>(q16, k16, vt16, h16);

  GemmIO io2;
  io2.bias[0] = (const float*)d_in[13];
  io2.bias[1] = (const float*)d_in[14];
  io2.bias[2] = (const float*)d_in[15];
  io2.out[0] = q16; io2.out[1] = k16; io2.out[2] = v16;
  gemm_kernel<bf16><<<dim3(128, 2, 3), 256, 0, stream>>>(h16, w16 + 3 * 65536, io2);
  transpose_kernel<<<dim3(64, 4, 4), 256, 0, stream>>>(v16, vt16);
  flash_kernel<<<256, 256, 0, stream>>>(q16, k16, vt16, h16);

  GemmIO io3;
  io3.bias[0] = (const float*)d_in[16];
  io3.bias[1] = (const float*)d_in[17];
  io3.bias[2] = nullptr;
  io3.out[0] = mu; io3.out[1] = lv; io3.out[2] = nullptr;
  gemm_kernel<float><<<dim3(128, 2, 2), 256, 0, stream>>>(h16, w16 + 6 * 65536, io3);

  gate_reduce<<<dim3(4, 4), 256, 0, stream>>>(h16, hbar);
  gate_final<<<1, 256, 0, stream>>>(hbar, Wg, bg, pg);
  epilogue_kernel<<<16384, 64, 0, stream>>>(x, eps, mu, lv, gamma, beta, out);
}

// Round 2
// 602.558 us; speedup vs baseline: 1.3961x; 1.3961x over previous
//
#include <hip/hip_runtime.h>
#include <hip/hip_bf16.h>
#include <cstdint>
#include <cstddef>

// Problem: B=4, S=4096, D=256 two-layer full attention + VAE head. fp32 I/O.
// Strategy: bf16 MFMA everywhere GEMM-shaped; fp32 softmax/epilogue.

#define S_LEN 4096
#define DMODEL 256
#define NBATCH 4
#define MTOT (NBATCH * S_LEN)  // 16384

typedef __bf16 bf16;
typedef __bf16 bf16x8 __attribute__((ext_vector_type(8)));
typedef float f32x4 __attribute__((ext_vector_type(4)));

__device__ __forceinline__ f32x4 mfma16(bf16x8 a, bf16x8 b, f32x4 c) {
  return __builtin_amdgcn_mfma_f32_16x16x32_bf16(a, b, c, 0, 0, 0);
}

// Async global->LDS, 16B per lane. LDS dest semantics: wave-uniform base + lane*16.
__device__ __forceinline__ void async16(bf16* lds, const bf16* g) {
  __builtin_amdgcn_global_load_lds(
      (const __attribute__((address_space(1))) unsigned int*)g,
      (__attribute__((address_space(3))) unsigned int*)lds, 16, 0, 0);
}

__device__ __forceinline__ unsigned short f2bfbits(float f) {
  return __builtin_bit_cast(unsigned short, (bf16)f);
}

// ---------------- cast kernels ----------------
__global__ void cast_x_kernel(const f32x4* __restrict__ src, ushort4* __restrict__ dst, int n4) {
  int i = blockIdx.x * 256 + threadIdx.x;
  if (i >= n4) return;
  f32x4 v = src[i];
  ushort4 o;
  o.x = f2bfbits(v[0]); o.y = f2bfbits(v[1]); o.z = f2bfbits(v[2]); o.w = f2bfbits(v[3]);
  dst[i] = o;
}

struct WPtrs { const float* p[8]; };

__global__ void cast_w_kernel(WPtrs wp, ushort4* __restrict__ dst) {
  int m = blockIdx.y;
  const f32x4* s = (const f32x4*)wp.p[m];
  int i = blockIdx.x * 256 + threadIdx.x;  // 0..16383
  f32x4 v = s[i];
  ushort4 o;
  o.x = f2bfbits(v[0]); o.y = f2bfbits(v[1]); o.z = f2bfbits(v[2]); o.w = f2bfbits(v[3]);
  dst[(size_t)m * 16384 + i] = o;
}

// ---------------- GEMM: out[m][n] = sum_k A[m][k]*W[n][k] + bias[n] ----------------
// A: [MTOT][256] bf16 row-major; W: [256][256] bf16 row-major (out-feature major).
// 128x128 tile, BK=64, 4 waves (each 64x64 = 4x4 of 16x16 MFMA).
// LDS rows of 64 elems = 8x16B chunks, XOR-swizzled: chunk slot c8s holds global chunk c8s^(r&7).
struct GemmIO {
  const float* bias[3];
  void* out[3];
};

template <typename OutT>
__global__ __launch_bounds__(256, 3) void gemm_kernel(const bf16* __restrict__ A,
                                                      const bf16* __restrict__ Wb, GemmIO io) {
  __shared__ bf16 ldsA[128 * 64];
  __shared__ bf16 ldsB[128 * 64];
  const int t = threadIdx.x;
  const int m0 = blockIdx.x * 128;
  const int n0 = blockIdx.y * 128;
  const bf16* W = Wb + (size_t)blockIdx.z * 65536;
  const int w = t >> 6, l = t & 63, lm = l & 15, q = l >> 4;
  const int wr = (w >> 1) * 64, wc = (w & 1) * 64;

  f32x4 acc[4][4] = {};
#pragma unroll 1
  for (int it = 0; it < 4; ++it) {
    const int k0 = it * 64;
#pragma unroll
    for (int c = 0; c < 4; ++c) {
      int i = c * 256 + t;
      int r = i >> 3, c8 = (i & 7) ^ (r & 7);
      async16(&ldsA[i * 8], A + (size_t)(m0 + r) * 256 + k0 + c8 * 8);
    }
#pragma unroll
    for (int c = 0; c < 4; ++c) {
      int i = c * 256 + t;
      int r = i >> 3, c8 = (i & 7) ^ (r & 7);
      async16(&ldsB[i * 8], W + (size_t)(n0 + r) * 256 + k0 + c8 * 8);
    }
    __syncthreads();
#pragma unroll
    for (int ks = 0; ks < 2; ++ks) {
      bf16x8 af[4], bfr[4];
#pragma unroll
      for (int i = 0; i < 4; ++i) {
        int ra = wr + i * 16 + lm;
        af[i] = *(const bf16x8*)&ldsA[ra * 64 + ((((ks << 2) + q) ^ (ra & 7)) << 3)];
        int rb = wc + i * 16 + lm;
        bfr[i] = *(const bf16x8*)&ldsB[rb * 64 + ((((ks << 2) + q) ^ (rb & 7)) << 3)];
      }
#pragma unroll
      for (int i = 0; i < 4; ++i)
#pragma unroll
        for (int jj = 0; jj < 4; ++jj) acc[i][jj] = mfma16(af[i], bfr[jj], acc[i][jj]);
    }
    __syncthreads();
  }
  const float* bias = io.bias[blockIdx.z];
  OutT* out = (OutT*)io.out[blockIdx.z];
#pragma unroll
  for (int jj = 0; jj < 4; ++jj) {
    int col = n0 + wc + jj * 16 + lm;
    float bv = bias[col];
#pragma unroll
    for (int i = 0; i < 4; ++i) {
      int row = m0 + wr + i * 16 + q * 4;
#pragma unroll
      for (int r = 0; r < 4; ++r)
        out[(size_t)(row + r) * 256 + col] = (OutT)(acc[i][jj][r] + bv);
    }
  }
}

// ---------------- transpose: V [B][S][256] -> Vt [B][256][S] ----------------
__global__ void transpose_kernel(const bf16* __restrict__ src, bf16* __restrict__ dst) {
  __shared__ bf16 tile[64][72];
  int s0 = blockIdx.x * 64, d0 = blockIdx.y * 64;
  size_t boff = (size_t)blockIdx.z * S_LEN * 256;
  size_t boffT = (size_t)blockIdx.z * 256 * S_LEN;
  int t = threadIdx.x;
#pragma unroll
  for (int rep = 0; rep < 16; ++rep) {
    int lin = rep * 256 + t;
    int r = lin >> 6, c = lin & 63;
    tile[r][c] = src[boff + (size_t)(s0 + r) * 256 + d0 + c];
  }
  __syncthreads();
#pragma unroll
  for (int rep = 0; rep < 16; ++rep) {
    int lin = rep * 256 + t;
    int r = lin >> 6, c = lin & 63;
    dst[boffT + (size_t)(d0 + r) * S_LEN + s0 + c] = tile[c][r];
  }
}

// ---------------- flash attention ----------------
// Grid 256 blocks (1/CU), 4 waves. BM=64 Q rows/block (16/wave), KV tiles of 64.
// K tile LDS rows = 256 elems = 32 chunks, swizzle c8s = c8 ^ (n&31).
// Vt tile LDS rows = 64 elems = 8 chunks, swizzle c8 ^ (d&7).
__device__ __forceinline__ void stage_kv(const bf16* __restrict__ Kb, const bf16* __restrict__ Vb,
                                         bf16* dK, bf16* dV, int kv0, int t) {
#pragma unroll
  for (int c = 0; c < 8; ++c) {
    int i = c * 256 + t;
    int n = i >> 5;
    int c8 = (i & 31) ^ (n & 31);
    async16(dK + i * 8, Kb + ((size_t)(kv0 + n) << 8) + (c8 << 3));
  }
#pragma unroll
  for (int c = 0; c < 8; ++c) {
    int i = c * 256 + t;
    int d = i >> 3;
    int c8 = (i & 7) ^ (d & 7);
    async16(dV + i * 8, Vb + (size_t)d * S_LEN + kv0 + (c8 << 3));
  }
}

__global__ __launch_bounds__(256, 1) void flash_kernel(const bf16* __restrict__ Q,
                                                       const bf16* __restrict__ K,
                                                       const bf16* __restrict__ Vt,
                                                       bf16* __restrict__ O) {
  __shared__ bf16 ldsK[2][64 * 256];   // 2 x 32KB
  __shared__ bf16 ldsV[2][256 * 64];   // 2 x 32KB
  __shared__ bf16 ldsP[4][16 * 80];    // 10KB, padded rows (160B, 16B-aligned)

  const int id = blockIdx.x;
  // XCD-aware swizzle: batch b pinned to XCDs {2b,2b+1} so K+V (4MB) stays L2-resident.
  const int xcd = id & 7;
  const int b = xcd >> 1;
  const int qt = (id >> 3) + ((xcd & 1) << 5);  // 0..63

  const bf16* Qb = Q + (size_t)b * S_LEN * 256;
  const bf16* Kb = K + (size_t)b * S_LEN * 256;
  const bf16* Vb = Vt + (size_t)b * 256 * S_LEN;
  bf16* Ob = O + (size_t)b * S_LEN * 256;

  const int t = threadIdx.x, w = t >> 6, l = t & 63, lm = l & 15, q = l >> 4;
  const float CL2 = 0.09016844005556021f;  // log2(e)/sqrt(D)=log2(e)/16

  // Q fragments persistent in registers: rows qt*64 + w*16 + lm, all 256 k.
  bf16x8 qf[8];
  {
    const bf16* qrow = Qb + (size_t)(qt * 64 + w * 16 + lm) * 256;
#pragma unroll
    for (int ks = 0; ks < 8; ++ks) qf[ks] = *(const bf16x8*)(qrow + ks * 32 + q * 8);
  }

  f32x4 o_acc[16] = {};
  float m_r[4] = {-INFINITY, -INFINITY, -INFINITY, -INFINITY};
  float l_r[4] = {0.f, 0.f, 0.f, 0.f};

  stage_kv(Kb, Vb, &ldsK[0][0], &ldsV[0][0], 0, t);

#pragma unroll 1
  for (int j = 0; j < 64; ++j) {
    const int cur = j & 1;
    __syncthreads();  // stage(j) complete (vmcnt drained); compute(j-1) done everywhere
    if (j + 1 < 64) stage_kv(Kb, Vb, &ldsK[cur ^ 1][0], &ldsV[cur ^ 1][0], (j + 1) * 64, t);

    // S = Q K^T (raw scores)
    f32x4 sv[4];
#pragma unroll
    for (int jt = 0; jt < 4; ++jt) {
      f32x4 s = {0.f, 0.f, 0.f, 0.f};
      const int n = jt * 16 + lm;
      const bf16* kr = &ldsK[cur][n * 256];
#pragma unroll
      for (int ks = 0; ks < 8; ++ks) {
        bf16x8 kf = *(const bf16x8*)(kr + ((((ks << 2) + q) ^ (n & 31)) << 3));
        s = mfma16(qf[ks], kf, s);
      }
      sv[jt] = s;
    }

    // online softmax (row r lives in reg r; cols spread over 16 lanes x 4 jt tiles)
    float mnew[4], alpha[4], rs[4];
#pragma unroll
    for (int r = 0; r < 4; ++r) {
      float mx = fmaxf(fmaxf(sv[0][r], sv[1][r]), fmaxf(sv[2][r], sv[3][r]));
      mx = fmaxf(mx, __shfl_xor(mx, 1, 64));
      mx = fmaxf(mx, __shfl_xor(mx, 2, 64));
      mx = fmaxf(mx, __shfl_xor(mx, 4, 64));
      mx = fmaxf(mx, __shfl_xor(mx, 8, 64));
      mnew[r] = fmaxf(m_r[r], mx);
      alpha[r] = exp2f((m_r[r] - mnew[r]) * CL2);
      m_r[r] = mnew[r];
      rs[r] = 0.f;
    }
#pragma unroll
    for (int jt = 0; jt < 4; ++jt)
#pragma unroll
      for (int r = 0; r < 4; ++r) {
        float p = exp2f((sv[jt][r] - mnew[r]) * CL2);
        sv[jt][r] = p;
        rs[r] += p;
      }
#pragma unroll
    for (int r = 0; r < 4; ++r) {
      float acc = rs[r];
      acc += __shfl_xor(acc, 1, 64);
      acc += __shfl_xor(acc, 2, 64);
      acc += __shfl_xor(acc, 4, 64);
      acc += __shfl_xor(acc, 8, 64);
      l_r[r] = l_r[r] * alpha[r] + acc;
    }
#pragma unroll
    for (int nt = 0; nt < 16; ++nt)
#pragma unroll
      for (int r = 0; r < 4; ++r) o_acc[nt][r] *= alpha[r];

    // P: C-layout -> LDS -> A-layout (per-wave private strip, no barrier needed)
#pragma unroll
    for (int jt = 0; jt < 4; ++jt)
#pragma unroll
      for (int r = 0; r < 4; ++r)
        ldsP[w][(q * 4 + r) * 80 + jt * 16 + lm] = (bf16)sv[jt][r];
    bf16x8 pa[2];
#pragma unroll
    for (int k2 = 0; k2 < 2; ++k2)
      pa[k2] = *(const bf16x8*)&ldsP[w][lm * 80 + k2 * 32 + q * 8];

    // O += P @ V  (B-operand from Vt rows: contiguous 16B, swizzled)
#pragma unroll
    for (int nt = 0; nt < 16; ++nt) {
      const int dd = nt * 16 + lm;
      const bf16* vr = &ldsV[cur][dd * 64];
#pragma unroll
      for (int k2 = 0; k2 < 2; ++k2) {
        bf16x8 vf = *(const bf16x8*)(vr + ((((k2 << 2) + q) ^ (dd & 7)) << 3));
        o_acc[nt] = mfma16(pa[k2], vf, o_acc[nt]);
      }
    }
  }

  float inv_l[4];
#pragma unroll
  for (int r = 0; r < 4; ++r) inv_l[r] = 1.0f / l_r[r];
  bf16* orow = Ob + (size_t)(qt * 64 + w * 16) * 256;
#pragma unroll
  for (int nt = 0; nt < 16; ++nt)
#pragma unroll
    for (int r = 0; r < 4; ++r)
      orow[(size_t)(q * 4 + r) * 256 + nt * 16 + lm] = (bf16)(o_acc[nt][r] * inv_l[r]);
}

// ---------------- gate: mean over S then dot Wg + sigmoid ----------------
// Stage 1: grid (64, NBATCH), 256 threads. Block handles 64 rows; thread t owns
// column t -> consecutive lanes read consecutive bf16 (coalesced 512B/row).
__global__ __launch_bounds__(256) void gate_partial(const bf16* __restrict__ h,
                                                    float* __restrict__ part) {
  int bb = blockIdx.y;
  const bf16* hb = h + (size_t)bb * S_LEN * 256 + (size_t)blockIdx.x * 64 * 256;
  int t = threadIdx.x;
  float acc = 0.f;
#pragma unroll 4
  for (int s = 0; s < 64; ++s) acc += (float)hb[s * 256 + t];
  part[((size_t)bb * 64 + blockIdx.x) * 256 + t] = acc;
}

// Stage 2: 4 blocks; block bb reduces part[bb][64][256], dots with Wg, sigmoid.
__global__ __launch_bounds__(256) void gate_final(const float* __restrict__ part,
                                                  const float* __restrict__ Wg,
                                                  const float* __restrict__ bg,
                                                  float* __restrict__ pg) {
  int bb = blockIdx.x, t = threadIdx.x;
  const float* p = part + (size_t)bb * 64 * 256;
  float acc = 0.f;
#pragma unroll 4
  for (int c = 0; c < 64; ++c) acc += p[c * 256 + t];
  acc *= Wg[t] * (1.0f / 4096.0f);
  __shared__ float red[256];
  red[t] = acc;
  __syncthreads();
  if (t < 64) {
    float a = red[t] + red[t + 64] + red[t + 128] + red[t + 192];
#pragma unroll
    for (int d = 1; d < 64; d <<= 1) a += __shfl_xor(a, d, 64);
    if (t == 0) pg[bb] = 1.0f / (1.0f + __expf(-(a + bg[0])));
  }
}

// ---------------- fused reparam + ELU + residual + LayerNorm ----------------
__global__ __launch_bounds__(64) void epilogue_kernel(const float* __restrict__ x,
                                                      const float* __restrict__ eps,
                                                      const float* __restrict__ mu,
                                                      const float* __restrict__ lv,
                                                      const float* __restrict__ gamma,
                                                      const float* __restrict__ beta,
                                                      float* __restrict__ out) {
  size_t base = (size_t)blockIdx.x * 256;
  int l = threadIdx.x;
  f32x4 xv = ((const f32x4*)(x + base))[l];
  f32x4 ev = ((const f32x4*)(eps + base))[l];
  f32x4 mv = ((const f32x4*)(mu + base))[l];
  f32x4 vv = ((const f32x4*)(lv + base))[l];
  f32x4 y;
  float s = 0.f, s2 = 0.f;
#pragma unroll
  for (int c = 0; c < 4; ++c) {
    float z = mv[c] + ev[c] * __expf(0.5f * vv[c]);
    z = z > 0.f ? z : (__expf(z) - 1.f);
    float yy = xv[c] + z;
    y[c] = yy;
    s += yy;
    s2 += yy * yy;
  }
#pragma unroll
  for (int d = 1; d < 64; d <<= 1) {
    s += __shfl_xor(s, d, 64);
    s2 += __shfl_xor(s2, d, 64);
  }
  float mean = s * (1.f / 256.f);
  float var = s2 * (1.f / 256.f) - mean * mean;
  float rstd = rsqrtf(var + 1e-5f);
  f32x4 gv = ((const f32x4*)gamma)[l];
  f32x4 bv = ((const f32x4*)beta)[l];
  f32x4 o;
#pragma unroll
  for (int c = 0; c < 4; ++c) o[c] = (y[c] - mean) * rstd * gv[c] + bv[c];
  ((f32x4*)(out + base))[l] = o;
}

// ---------------- launch ----------------
extern "C" void kernel_launch(void* const* d_in, const int* in_sizes, int n_in, void* d_out,
                              int out_size, void* d_ws, size_t ws_size, hipStream_t stream) {
  const float* x = (const float*)d_in[0];
  const float* eps = (const float*)d_in[1];
  const float* Wg = (const float*)d_in[18];
  const float* bg = (const float*)d_in[19];
  const float* gamma = (const float*)d_in[20];
  const float* beta = (const float*)d_in[21];

  char* ws = (char*)d_ws;
  bf16* x16 = (bf16*)(ws);                  // 8 MB
  bf16* q16 = (bf16*)(ws + 8388608);        // 8 MB
  bf16* k16 = (bf16*)(ws + 16777216);       // 8 MB
  bf16* v16 = (bf16*)(ws + 25165824);       // 8 MB
  bf16* vt16 = (bf16*)(ws + 33554432);      // 8 MB
  bf16* h16 = (bf16*)(ws + 41943040);       // 8 MB
  bf16* w16 = (bf16*)(ws + 50331648);       // 1 MB (8 x 256x256 bf16)
  float* gpart = (float*)(ws + 51380224);   // 256 KB (4 x 64 x 256 fp32)

  float* out = (float*)d_out;
  float* mu = out + 4194304;
  float* lv = out + 8388608;
  float* pg = out + 12582912;

  cast_x_kernel<<<4096, 256, 0, stream>>>((const f32x4*)x, (ushort4*)x16, 1048576);
  WPtrs wp;
  for (int i = 0; i < 8; ++i) wp.p[i] = (const float*)d_in[2 + i];
  cast_w_kernel<<<dim3(64, 8), 256, 0, stream>>>(wp, (ushort4*)w16);

  GemmIO io1;
  io1.bias[0] = (const float*)d_in[10];
  io1.bias[1] = (const float*)d_in[11];
  io1.bias[2] = (const float*)d_in[12];
  io1.out[0] = q16; io1.out[1] = k16; io1.out[2] = v16;
  gemm_kernel<bf16><<<dim3(128, 2, 3), 256, 0, stream>>>(x16, w16, io1);
  transpose_kernel<<<dim3(64, 4, 4), 256, 0, stream>>>(v16, vt16);
  flash_kernel<<<256, 256, 0, stream>>>(q16, k16, vt16, h16);

  GemmIO io2;
  io2.bias[0] = (const float*)d_in[13];
  io2.bias[1] = (const float*)d_in[14];
  io2.bias[2] = (const float*)d_in[15];
  io2.out[0] = q16; io2.out[1] = k16; io2.out[2] = v16;
  gemm_kernel<bf16><<<dim3(128, 2, 3), 256, 0, stream>>>(h16, w16 + 3 * 65536, io2);
  transpose_kernel<<<dim3(64, 4, 4), 256, 0, stream>>>(v16, vt16);
  flash_kernel<<<256, 256, 0, stream>>>(q16, k16, vt16, h16);

  GemmIO io3;
  io3.bias[0] = (const float*)d_in[16];
  io3.bias[1] = (const float*)d_in[17];
  io3.bias[2] = nullptr;
  io3.out[0] = mu; io3.out[1] = lv; io3.out[2] = nullptr;
  gemm_kernel<float><<<dim3(128, 2, 2), 256, 0, stream>>>(h16, w16 + 6 * 65536, io3);

  gate_partial<<<dim3(64, 4), 256, 0, stream>>>(h16, gpart);
  gate_final<<<4, 256, 0, stream>>>(gpart, Wg, bg, pg);
  epilogue_kernel<<<16384, 64, 0, stream>>>(x, eps, mu, lv, gamma, beta, out);
}

// Round 3
// 522.808 us; speedup vs baseline: 1.6091x; 1.1525x over previous
//
#include <hip/hip_runtime.h>
#include <hip/hip_bf16.h>
#include <cstdint>
#include <cstddef>

// Problem: B=4, S=4096, D=256 two-layer full attention + VAE head. fp32 I/O.
// Strategy: bf16 MFMA everywhere GEMM-shaped; fp32 softmax/epilogue.

#define S_LEN 4096
#define DMODEL 256
#define NBATCH 4
#define MTOT (NBATCH * S_LEN)  // 16384

typedef __bf16 bf16;
typedef __bf16 bf16x8 __attribute__((ext_vector_type(8)));
typedef float f32x4 __attribute__((ext_vector_type(4)));

__device__ __forceinline__ f32x4 mfma16(bf16x8 a, bf16x8 b, f32x4 c) {
  return __builtin_amdgcn_mfma_f32_16x16x32_bf16(a, b, c, 0, 0, 0);
}

// Async global->LDS, 16B per lane. LDS dest semantics: wave-uniform base + lane*16.
__device__ __forceinline__ void async16(bf16* lds, const bf16* g) {
  __builtin_amdgcn_global_load_lds(
      (const __attribute__((address_space(1))) unsigned int*)g,
      (__attribute__((address_space(3))) unsigned int*)lds, 16, 0, 0);
}

__device__ __forceinline__ unsigned short f2bfbits(float f) {
  return __builtin_bit_cast(unsigned short, (bf16)f);
}

// ---------------- cast kernels ----------------
__global__ void cast_x_kernel(const f32x4* __restrict__ src, ushort4* __restrict__ dst, int n4) {
  int i = blockIdx.x * 256 + threadIdx.x;
  if (i >= n4) return;
  f32x4 v = src[i];
  ushort4 o;
  o.x = f2bfbits(v[0]); o.y = f2bfbits(v[1]); o.z = f2bfbits(v[2]); o.w = f2bfbits(v[3]);
  dst[i] = o;
}

struct WPtrs { const float* p[8]; };

__global__ void cast_w_kernel(WPtrs wp, ushort4* __restrict__ dst) {
  int m = blockIdx.y;
  const f32x4* s = (const f32x4*)wp.p[m];
  int i = blockIdx.x * 256 + threadIdx.x;  // 0..16383
  f32x4 v = s[i];
  ushort4 o;
  o.x = f2bfbits(v[0]); o.y = f2bfbits(v[1]); o.z = f2bfbits(v[2]); o.w = f2bfbits(v[3]);
  dst[(size_t)m * 16384 + i] = o;
}

// ---------------- GEMM: out[m][n] = sum_k A[m][k]*W[n][k] + bias[n] ----------------
struct GemmIO {
  const float* bias[3];
  void* out[3];
};

template <typename OutT>
__global__ __launch_bounds__(256, 3) void gemm_kernel(const bf16* __restrict__ A,
                                                      const bf16* __restrict__ Wb, GemmIO io) {
  __shared__ bf16 ldsA[128 * 64];
  __shared__ bf16 ldsB[128 * 64];
  const int t = threadIdx.x;
  const int m0 = blockIdx.x * 128;
  const int n0 = blockIdx.y * 128;
  const bf16* W = Wb + (size_t)blockIdx.z * 65536;
  const int w = t >> 6, l = t & 63, lm = l & 15, q = l >> 4;
  const int wr = (w >> 1) * 64, wc = (w & 1) * 64;

  f32x4 acc[4][4] = {};
#pragma unroll 1
  for (int it = 0; it < 4; ++it) {
    const int k0 = it * 64;
#pragma unroll
    for (int c = 0; c < 4; ++c) {
      int i = c * 256 + t;
      int r = i >> 3, c8 = (i & 7) ^ (r & 7);
      async16(&ldsA[i * 8], A + (size_t)(m0 + r) * 256 + k0 + c8 * 8);
    }
#pragma unroll
    for (int c = 0; c < 4; ++c) {
      int i = c * 256 + t;
      int r = i >> 3, c8 = (i & 7) ^ (r & 7);
      async16(&ldsB[i * 8], W + (size_t)(n0 + r) * 256 + k0 + c8 * 8);
    }
    __syncthreads();
#pragma unroll
    for (int ks = 0; ks < 2; ++ks) {
      bf16x8 af[4], bfr[4];
#pragma unroll
      for (int i = 0; i < 4; ++i) {
        int ra = wr + i * 16 + lm;
        af[i] = *(const bf16x8*)&ldsA[ra * 64 + ((((ks << 2) + q) ^ (ra & 7)) << 3)];
        int rb = wc + i * 16 + lm;
        bfr[i] = *(const bf16x8*)&ldsB[rb * 64 + ((((ks << 2) + q) ^ (rb & 7)) << 3)];
      }
#pragma unroll
      for (int i = 0; i < 4; ++i)
#pragma unroll
        for (int jj = 0; jj < 4; ++jj) acc[i][jj] = mfma16(af[i], bfr[jj], acc[i][jj]);
    }
    __syncthreads();
  }
  const float* bias = io.bias[blockIdx.z];
  OutT* out = (OutT*)io.out[blockIdx.z];
#pragma unroll
  for (int jj = 0; jj < 4; ++jj) {
    int col = n0 + wc + jj * 16 + lm;
    float bv = bias[col];
#pragma unroll
    for (int i = 0; i < 4; ++i) {
      int row = m0 + wr + i * 16 + q * 4;
#pragma unroll
      for (int r = 0; r < 4; ++r)
        out[(size_t)(row + r) * 256 + col] = (OutT)(acc[i][jj][r] + bv);
    }
  }
}

// ---------------- transpose: V [B][S][256] -> Vt [B][256][S] ----------------
__global__ void transpose_kernel(const bf16* __restrict__ src, bf16* __restrict__ dst) {
  __shared__ bf16 tile[64][72];
  int s0 = blockIdx.x * 64, d0 = blockIdx.y * 64;
  size_t boff = (size_t)blockIdx.z * S_LEN * 256;
  size_t boffT = (size_t)blockIdx.z * 256 * S_LEN;
  int t = threadIdx.x;
#pragma unroll
  for (int rep = 0; rep < 16; ++rep) {
    int lin = rep * 256 + t;
    int r = lin >> 6, c = lin & 63;
    tile[r][c] = src[boff + (size_t)(s0 + r) * 256 + d0 + c];
  }
  __syncthreads();
#pragma unroll
  for (int rep = 0; rep < 16; ++rep) {
    int lin = rep * 256 + t;
    int r = lin >> 6, c = lin & 63;
    dst[boffT + (size_t)(d0 + r) * S_LEN + s0 + c] = tile[c][r];
  }
}

// ---------------- flash attention v2 ----------------
// 256 blocks (1/CU), 512 threads = 8 waves = 2 waves/SIMD. BM=64 Q rows/block.
// Wave w: qg=w&3 owns Q rows qg*16..+15; hf=w>>2 owns KV half-columns hf*32..+31
// of each 64-col KV tile. Private online-softmax state per wave; merged once at end.
// K tile LDS rows = 256 elems = 32 chunks, swizzle c8^(n&31).
// Vt tile LDS rows = 64 elems = 8 chunks, swizzle c8^(d&7).
__global__ __launch_bounds__(512, 2) void flash_kernel(const bf16* __restrict__ Q,
                                                       const bf16* __restrict__ K,
                                                       const bf16* __restrict__ Vt,
                                                       bf16* __restrict__ O) {
  __shared__ bf16 ldsK[2][64 * 256];  // 2 x 32KB
  __shared__ bf16 ldsV[2][256 * 64];  // 2 x 32KB
  __shared__ bf16 ldsP[8][16 * 40];   // 10KB, 80B rows (16B-aligned)

  const int id = blockIdx.x;
  // XCD-aware swizzle: batch b pinned to XCDs {2b,2b+1} so K+V (4MB) stays L2-resident.
  const int xcd = id & 7;
  const int b = xcd >> 1;
  const int qt = (id >> 3) + ((xcd & 1) << 5);  // 0..63

  const bf16* Qb = Q + (size_t)b * S_LEN * 256;
  const bf16* Kb = K + (size_t)b * S_LEN * 256;
  const bf16* Vb = Vt + (size_t)b * 256 * S_LEN;
  bf16* Ob = O + (size_t)b * S_LEN * 256;

  const int t = threadIdx.x, w = t >> 6, l = t & 63, lm = l & 15, q = l >> 4;
  const int qg = w & 3, hf = w >> 2;
  const float CL2 = 0.09016844005556021f;  // log2(e)/sqrt(D) = log2(e)/16

  // ---- j-invariant offsets (registers) ----
  // staging: 512 threads x 4 chunks each for K and V
  int i8[4], gk[4], gv[4];
#pragma unroll
  for (int c = 0; c < 4; ++c) {
    int i = c * 512 + t;
    i8[c] = i * 8;
    int n = i >> 5, c8 = (i & 31) ^ (n & 31);
    gk[c] = n * 256 + c8 * 8;
    int d2 = i >> 3, c82 = (i & 7) ^ (d2 & 7);
    gv[c] = d2 * S_LEN + c82 * 8;
  }
  // K fragment offsets: jt in {0,1}, ks in 0..7
  int koff[2][8];
#pragma unroll
  for (int jt = 0; jt < 2; ++jt) {
    int n = hf * 32 + jt * 16 + lm;
#pragma unroll
    for (int ks = 0; ks < 8; ++ks)
      koff[jt][ks] = n * 256 + ((((ks << 2) + q) ^ (n & 31)) << 3);
  }
  // V fragment offsets: nt in 0..15 (full D), k-chunk hf*4+q
  int voff[16];
#pragma unroll
  for (int nt = 0; nt < 16; ++nt) {
    int dd = nt * 16 + lm;
    voff[nt] = dd * 64 + ((((hf << 2) + q) ^ (dd & 7)) << 3);
  }

  // Q fragments persistent in registers: rows qt*64 + qg*16 + lm, all 256 k.
  bf16x8 qf[8];
  {
    const bf16* qrow = Qb + (size_t)(qt * 64 + qg * 16 + lm) * 256;
#pragma unroll
    for (int ks = 0; ks < 8; ++ks) qf[ks] = *(const bf16x8*)(qrow + ks * 32 + q * 8);
  }

  f32x4 o_acc[16] = {};
  float m_r[4] = {-INFINITY, -INFINITY, -INFINITY, -INFINITY};
  float l_r[4] = {0.f, 0.f, 0.f, 0.f};

  // stage tile 0 into buffer 0
#pragma unroll
  for (int c = 0; c < 4; ++c) {
    async16(&ldsK[0][0] + i8[c], Kb + gk[c]);
    async16(&ldsV[0][0] + i8[c], Vb + gv[c]);
  }

#pragma unroll 1
  for (int j = 0; j < 64; ++j) {
    const int cur = j & 1;
    __syncthreads();  // stage(j) drained; compute(j-1) done everywhere
    if (j + 1 < 64) {
      const bf16* kg = Kb + (j + 1) * 64 * 256;
      const bf16* vg = Vb + (j + 1) * 64;
      bf16* dK = &ldsK[cur ^ 1][0];
      bf16* dV = &ldsV[cur ^ 1][0];
#pragma unroll
      for (int c = 0; c < 4; ++c) {
        async16(dK + i8[c], kg + gk[c]);
        async16(dV + i8[c], vg + gv[c]);
      }
    }

    // S = Q K^T over this wave's 32 KV columns
    const bf16* kbase = &ldsK[cur][0];
    f32x4 sv[2];
#pragma unroll
    for (int jt = 0; jt < 2; ++jt) {
      f32x4 s = {0.f, 0.f, 0.f, 0.f};
#pragma unroll
      for (int ks = 0; ks < 8; ++ks) {
        bf16x8 kf = *(const bf16x8*)(kbase + koff[jt][ks]);
        s = mfma16(qf[ks], kf, s);
      }
      sv[jt] = s;
    }

    // online softmax over the 32-col strip (cols spread over 16 lanes x 2 jt)
    float mnew[4], alpha[4], rs[4];
    bool same = true;
#pragma unroll
    for (int r = 0; r < 4; ++r) {
      float mx = fmaxf(sv[0][r], sv[1][r]);
      mx = fmaxf(mx, __shfl_xor(mx, 1, 64));
      mx = fmaxf(mx, __shfl_xor(mx, 2, 64));
      mx = fmaxf(mx, __shfl_xor(mx, 4, 64));
      mx = fmaxf(mx, __shfl_xor(mx, 8, 64));
      mnew[r] = fmaxf(m_r[r], mx);
      same = same && (mnew[r] == m_r[r]);
      alpha[r] = __builtin_amdgcn_exp2f((m_r[r] - mnew[r]) * CL2);
      m_r[r] = mnew[r];
      rs[r] = 0.f;
    }
#pragma unroll
    for (int jt = 0; jt < 2; ++jt)
#pragma unroll
      for (int r = 0; r < 4; ++r) {
        float p = __builtin_amdgcn_exp2f((sv[jt][r] - mnew[r]) * CL2);
        sv[jt][r] = p;
        rs[r] += p;
      }
#pragma unroll
    for (int r = 0; r < 4; ++r) {
      float acc = rs[r];
      acc += __shfl_xor(acc, 1, 64);
      acc += __shfl_xor(acc, 2, 64);
      acc += __shfl_xor(acc, 4, 64);
      acc += __shfl_xor(acc, 8, 64);
      rs[r] = acc;
    }
    if (!__all(same)) {  // rare: running max moved -> rescale
#pragma unroll
      for (int nt = 0; nt < 16; ++nt)
#pragma unroll
        for (int r = 0; r < 4; ++r) o_acc[nt][r] *= alpha[r];
#pragma unroll
      for (int r = 0; r < 4; ++r) l_r[r] *= alpha[r];
    }
#pragma unroll
    for (int r = 0; r < 4; ++r) l_r[r] += rs[r];

    // P: C-layout -> LDS -> A-layout (per-wave private strip)
#pragma unroll
    for (int jt = 0; jt < 2; ++jt)
#pragma unroll
      for (int r = 0; r < 4; ++r)
        ldsP[w][(q * 4 + r) * 40 + jt * 16 + lm] = (bf16)sv[jt][r];
    bf16x8 pa = *(const bf16x8*)&ldsP[w][lm * 40 + q * 8];

    // O += P @ V over this wave's 32 KV rows (full D)
    const bf16* vbase = &ldsV[cur][0];
#pragma unroll
    for (int nt = 0; nt < 16; ++nt) {
      bf16x8 vf = *(const bf16x8*)(vbase + voff[nt]);
      o_acc[nt] = mfma16(pa, vf, o_acc[nt]);
    }
  }

  // ---- merge the two KV-half states per Q-group ----
  __syncthreads();
  float* mlbuf = (float*)&ldsP[0][0];  // [hf][qg][row16][{m,l}] = 1KB
  if (lm == 0) {
#pragma unroll
    for (int r = 0; r < 4; ++r) {
      int idx = (((hf << 2) | qg) * 16 + q * 4 + r) * 2;
      mlbuf[idx] = m_r[r];
      mlbuf[idx + 1] = l_r[r];
    }
  }
  __syncthreads();
  float asf[4], lcomb[4];
#pragma unroll
  for (int r = 0; r < 4; ++r) {
    int idx = ((((1 - hf) << 2) | qg) * 16 + q * 4 + r) * 2;
    float mo = mlbuf[idx], lo = mlbuf[idx + 1];
    float mm = fmaxf(m_r[r], mo);
    asf[r] = __builtin_amdgcn_exp2f((m_r[r] - mm) * CL2);
    float aof = __builtin_amdgcn_exp2f((mo - mm) * CL2);
    lcomb[r] = l_r[r] * asf[r] + lo * aof;
  }
#pragma unroll
  for (int nt = 0; nt < 16; ++nt)
#pragma unroll
    for (int r = 0; r < 4; ++r) o_acc[nt][r] *= asf[r];

  float* obuf = (float*)&ldsK[0][0];  // [qg][nt][lane] f32x4 = 64KB
  if (hf == 1) {
#pragma unroll
    for (int nt = 0; nt < 16; ++nt)
      *(f32x4*)&obuf[(((qg << 4) | nt) * 64 + l) * 4] = o_acc[nt];
  }
  __syncthreads();
  if (hf == 0) {
    float inv_l[4];
#pragma unroll
    for (int r = 0; r < 4; ++r) inv_l[r] = 1.0f / lcomb[r];
    bf16* orow = Ob + (size_t)(qt * 64 + qg * 16) * 256;
#pragma unroll
    for (int nt = 0; nt < 16; ++nt) {
      f32x4 oo = *(const f32x4*)&obuf[(((qg << 4) | nt) * 64 + l) * 4];
#pragma unroll
      for (int r = 0; r < 4; ++r)
        orow[(size_t)(q * 4 + r) * 256 + nt * 16 + lm] =
            (bf16)((o_acc[nt][r] + oo[r]) * inv_l[r]);
    }
  }
}

// ---------------- gate: mean over S then dot Wg + sigmoid ----------------
__global__ __launch_bounds__(256) void gate_partial(const bf16* __restrict__ h,
                                                    float* __restrict__ part) {
  int bb = blockIdx.y;
  const bf16* hb = h + (size_t)bb * S_LEN * 256 + (size_t)blockIdx.x * 64 * 256;
  int t = threadIdx.x;
  float acc = 0.f;
#pragma unroll 4
  for (int s = 0; s < 64; ++s) acc += (float)hb[s * 256 + t];
  part[((size_t)bb * 64 + blockIdx.x) * 256 + t] = acc;
}

__global__ __launch_bounds__(256) void gate_final(const float* __restrict__ part,
                                                  const float* __restrict__ Wg,
                                                  const float* __restrict__ bg,
                                                  float* __restrict__ pg) {
  int bb = blockIdx.x, t = threadIdx.x;
  const float* p = part + (size_t)bb * 64 * 256;
  float acc = 0.f;
#pragma unroll 4
  for (int c = 0; c < 64; ++c) acc += p[c * 256 + t];
  acc *= Wg[t] * (1.0f / 4096.0f);
  __shared__ float red[256];
  red[t] = acc;
  __syncthreads();
  if (t < 64) {
    float a = red[t] + red[t + 64] + red[t + 128] + red[t + 192];
#pragma unroll
    for (int d = 1; d < 64; d <<= 1) a += __shfl_xor(a, d, 64);
    if (t == 0) pg[bb] = 1.0f / (1.0f + __expf(-(a + bg[0])));
  }
}

// ---------------- fused reparam + ELU + residual + LayerNorm ----------------
__global__ __launch_bounds__(64) void epilogue_kernel(const float* __restrict__ x,
                                                      const float* __restrict__ eps,
                                                      const float* __restrict__ mu,
                                                      const float* __restrict__ lv,
                                                      const float* __restrict__ gamma,
                                                      const float* __restrict__ beta,
                                                      float* __restrict__ out) {
  size_t base = (size_t)blockIdx.x * 256;
  int l = threadIdx.x;
  f32x4 xv = ((const f32x4*)(x + base))[l];
  f32x4 ev = ((const f32x4*)(eps + base))[l];
  f32x4 mv = ((const f32x4*)(mu + base))[l];
  f32x4 vv = ((const f32x4*)(lv + base))[l];
  f32x4 y;
  float s = 0.f, s2 = 0.f;
#pragma unroll
  for (int c = 0; c < 4; ++c) {
    float z = mv[c] + ev[c] * __expf(0.5f * vv[c]);
    z = z > 0.f ? z : (__expf(z) - 1.f);
    float yy = xv[c] + z;
    y[c] = yy;
    s += yy;
    s2 += yy * yy;
  }
#pragma unroll
  for (int d = 1; d < 64; d <<= 1) {
    s += __shfl_xor(s, d, 64);
    s2 += __shfl_xor(s2, d, 64);
  }
  float mean = s * (1.f / 256.f);
  float var = s2 * (1.f / 256.f) - mean * mean;
  float rstd = rsqrtf(var + 1e-5f);
  f32x4 gv = ((const f32x4*)gamma)[l];
  f32x4 bv = ((const f32x4*)beta)[l];
  f32x4 o;
#pragma unroll
  for (int c = 0; c < 4; ++c) o[c] = (y[c] - mean) * rstd * gv[c] + bv[c];
  ((f32x4*)(out + base))[l] = o;
}

// ---------------- launch ----------------
extern "C" void kernel_launch(void* const* d_in, const int* in_sizes, int n_in, void* d_out,
                              int out_size, void* d_ws, size_t ws_size, hipStream_t stream) {
  const float* x = (const float*)d_in[0];
  const float* eps = (const float*)d_in[1];
  const float* Wg = (const float*)d_in[18];
  const float* bg = (const float*)d_in[19];
  const float* gamma = (const float*)d_in[20];
  const float* beta = (const float*)d_in[21];

  char* ws = (char*)d_ws;
  bf16* x16 = (bf16*)(ws);                  // 8 MB
  bf16* q16 = (bf16*)(ws + 8388608);        // 8 MB
  bf16* k16 = (bf16*)(ws + 16777216);       // 8 MB
  bf16* v16 = (bf16*)(ws + 25165824);       // 8 MB
  bf16* vt16 = (bf16*)(ws + 33554432);      // 8 MB
  bf16* h16 = (bf16*)(ws + 41943040);       // 8 MB
  bf16* w16 = (bf16*)(ws + 50331648);       // 1 MB (8 x 256x256 bf16)
  float* gpart = (float*)(ws + 51380224);   // 256 KB

  float* out = (float*)d_out;
  float* mu = out + 4194304;
  float* lv = out + 8388608;
  float* pg = out + 12582912;

  cast_x_kernel<<<4096, 256, 0, stream>>>((const f32x4*)x, (ushort4*)x16, 1048576);
  WPtrs wp;
  for (int i = 0; i < 8; ++i) wp.p[i] = (const float*)d_in[2 + i];
  cast_w_kernel<<<dim3(64, 8), 256, 0, stream>>>(wp, (ushort4*)w16);

  GemmIO io1;
  io1.bias[0] = (const float*)d_in[10];
  io1.bias[1] = (const float*)d_in[11];
  io1.bias[2] = (const float*)d_in[12];
  io1.out[0] = q16; io1.out[1] = k16; io1.out[2] = v16;
  gemm_kernel<bf16><<<dim3(128, 2, 3), 256, 0, stream>>>(x16, w16, io1);
  transpose_kernel<<<dim3(64, 4, 4), 256, 0, stream>>>(v16, vt16);
  flash_kernel<<<256, 512, 0, stream>>>(q16, k16, vt16, h16);

  GemmIO io2;
  io2.bias[0] = (const float*)d_in[13];
  io2.bias[1] = (const float*)d_in[14];
  io2.bias[2] = (const float*)d_in[15];
  io2.out[0] = q16; io2.out[1] = k16; io2.out[2] = v16;
  gemm_kernel<bf16><<<dim3(128, 2, 3), 256, 0, stream>>>(h16, w16 + 3 * 65536, io2);
  transpose_kernel<<<dim3(64, 4, 4), 256, 0, stream>>>(v16, vt16);
  flash_kernel<<<256, 512, 0, stream>>>(q16, k16, vt16, h16);

  GemmIO io3;
  io3.bias[0] = (const float*)d_in[16];
  io3.bias[1] = (const float*)d_in[17];
  io3.bias[2] = nullptr;
  io3.out[0] = mu; io3.out[1] = lv; io3.out[2] = nullptr;
  gemm_kernel<float><<<dim3(128, 2, 2), 256, 0, stream>>>(h16, w16 + 6 * 65536, io3);

  gate_partial<<<dim3(64, 4), 256, 0, stream>>>(h16, gpart);
  gate_final<<<4, 256, 0, stream>>>(gpart, Wg, bg, pg);
  epilogue_kernel<<<16384, 64, 0, stream>>>(x, eps, mu, lv, gamma, beta, out);
}

// Round 4
// 430.884 us; speedup vs baseline: 1.9524x; 1.2133x over previous
//
#include <hip/hip_runtime.h>
#include <hip/hip_bf16.h>
#include <cstdint>
#include <cstddef>

// Problem: B=4, S=4096, D=256 two-layer full attention + VAE head. fp32 I/O.
// Strategy: bf16 MFMA everywhere GEMM-shaped; fp32 softmax/epilogue.

#define S_LEN 4096
#define DMODEL 256
#define NBATCH 4
#define MTOT (NBATCH * S_LEN)  // 16384

typedef __bf16 bf16;
typedef __bf16 bf16x8 __attribute__((ext_vector_type(8)));
typedef float f32x4 __attribute__((ext_vector_type(4)));

__device__ __forceinline__ f32x4 mfma16(bf16x8 a, bf16x8 b, f32x4 c) {
  return __builtin_amdgcn_mfma_f32_16x16x32_bf16(a, b, c, 0, 0, 0);
}

// Async global->LDS, 16B per lane. LDS dest semantics: wave-uniform base + lane*16.
__device__ __forceinline__ void async16(bf16* lds, const bf16* g) {
  __builtin_amdgcn_global_load_lds(
      (const __attribute__((address_space(1))) unsigned int*)g,
      (__attribute__((address_space(3))) unsigned int*)lds, 16, 0, 0);
}

__device__ __forceinline__ unsigned short f2bfbits(float f) {
  return __builtin_bit_cast(unsigned short, (bf16)f);
}

// ---------------- cast kernels ----------------
__global__ void cast_x_kernel(const f32x4* __restrict__ src, ushort4* __restrict__ dst, int n4) {
  int i = blockIdx.x * 256 + threadIdx.x;
  if (i >= n4) return;
  f32x4 v = src[i];
  ushort4 o;
  o.x = f2bfbits(v[0]); o.y = f2bfbits(v[1]); o.z = f2bfbits(v[2]); o.w = f2bfbits(v[3]);
  dst[i] = o;
}

struct WPtrs { const float* p[8]; };

__global__ void cast_w_kernel(WPtrs wp, ushort4* __restrict__ dst) {
  int m = blockIdx.y;
  const f32x4* s = (const f32x4*)wp.p[m];
  int i = blockIdx.x * 256 + threadIdx.x;  // 0..16383
  f32x4 v = s[i];
  ushort4 o;
  o.x = f2bfbits(v[0]); o.y = f2bfbits(v[1]); o.z = f2bfbits(v[2]); o.w = f2bfbits(v[3]);
  dst[(size_t)m * 16384 + i] = o;
}

// ---------------- GEMM: out[m][n] = sum_k A[m][k]*W[n][k] + bias[n] ----------------
struct GemmIO {
  const float* bias[3];
  void* out[3];
};

template <typename OutT>
__global__ __launch_bounds__(256, 3) void gemm_kernel(const bf16* __restrict__ A,
                                                      const bf16* __restrict__ Wb, GemmIO io) {
  __shared__ bf16 ldsA[128 * 64];
  __shared__ bf16 ldsB[128 * 64];
  const int t = threadIdx.x;
  const int m0 = blockIdx.x * 128;
  const int n0 = blockIdx.y * 128;
  const bf16* W = Wb + (size_t)blockIdx.z * 65536;
  const int w = t >> 6, l = t & 63, lm = l & 15, q = l >> 4;
  const int wr = (w >> 1) * 64, wc = (w & 1) * 64;

  f32x4 acc[4][4] = {};
#pragma unroll 1
  for (int it = 0; it < 4; ++it) {
    const int k0 = it * 64;
#pragma unroll
    for (int c = 0; c < 4; ++c) {
      int i = c * 256 + t;
      int r = i >> 3, c8 = (i & 7) ^ (r & 7);
      async16(&ldsA[i * 8], A + (size_t)(m0 + r) * 256 + k0 + c8 * 8);
    }
#pragma unroll
    for (int c = 0; c < 4; ++c) {
      int i = c * 256 + t;
      int r = i >> 3, c8 = (i & 7) ^ (r & 7);
      async16(&ldsB[i * 8], W + (size_t)(n0 + r) * 256 + k0 + c8 * 8);
    }
    __syncthreads();
#pragma unroll
    for (int ks = 0; ks < 2; ++ks) {
      bf16x8 af[4], bfr[4];
#pragma unroll
      for (int i = 0; i < 4; ++i) {
        int ra = wr + i * 16 + lm;
        af[i] = *(const bf16x8*)&ldsA[ra * 64 + ((((ks << 2) + q) ^ (ra & 7)) << 3)];
        int rb = wc + i * 16 + lm;
        bfr[i] = *(const bf16x8*)&ldsB[rb * 64 + ((((ks << 2) + q) ^ (rb & 7)) << 3)];
      }
#pragma unroll
      for (int i = 0; i < 4; ++i)
#pragma unroll
        for (int jj = 0; jj < 4; ++jj) acc[i][jj] = mfma16(af[i], bfr[jj], acc[i][jj]);
    }
    __syncthreads();
  }
  const float* bias = io.bias[blockIdx.z];
  OutT* out = (OutT*)io.out[blockIdx.z];
#pragma unroll
  for (int jj = 0; jj < 4; ++jj) {
    int col = n0 + wc + jj * 16 + lm;
    float bv = bias[col];
#pragma unroll
    for (int i = 0; i < 4; ++i) {
      int row = m0 + wr + i * 16 + q * 4;
#pragma unroll
      for (int r = 0; r < 4; ++r)
        out[(size_t)(row + r) * 256 + col] = (OutT)(acc[i][jj][r] + bv);
    }
  }
}

// ---------------- transpose: V [B][S][256] -> Vt [B][256][S] ----------------
__global__ void transpose_kernel(const bf16* __restrict__ src, bf16* __restrict__ dst) {
  __shared__ bf16 tile[64][72];
  int s0 = blockIdx.x * 64, d0 = blockIdx.y * 64;
  size_t boff = (size_t)blockIdx.z * S_LEN * 256;
  size_t boffT = (size_t)blockIdx.z * 256 * S_LEN;
  int t = threadIdx.x;
#pragma unroll
  for (int rep = 0; rep < 16; ++rep) {
    int lin = rep * 256 + t;
    int r = lin >> 6, c = lin & 63;
    tile[r][c] = src[boff + (size_t)(s0 + r) * 256 + d0 + c];
  }
  __syncthreads();
#pragma unroll
  for (int rep = 0; rep < 16; ++rep) {
    int lin = rep * 256 + t;
    int r = lin >> 6, c = lin & 63;
    dst[boffT + (size_t)(d0 + r) * S_LEN + s0 + c] = tile[c][r];
  }
}

// ---------------- flash attention v3 ----------------
// 256 blocks (1/CU), 512 threads = 8 waves = 2 waves/SIMD. BM=64 Q rows/block.
// Wave w: qg=w&3 owns Q rows qg*16..+15; hf=w>>2 owns KV half-columns hf*32..+31.
// No online max (scores are O(1); exp2(s*log2e/16) overflows only at |s|>1400).
// l accumulated via ones-column MFMA; cross-half merge is a plain add.
// Swizzle ^(row&7) on 16B chunks (same banking as ^(row&31), but V reads collapse
// to ONE VGPR base + literal offsets, K reads to 8 bases + literal jt/cur offsets).
__global__ __launch_bounds__(512, 2) void flash_kernel(const bf16* __restrict__ Q,
                                                       const bf16* __restrict__ K,
                                                       const bf16* __restrict__ Vt,
                                                       bf16* __restrict__ O) {
  __shared__ bf16 ldsK[2][64 * 256];  // 2 x 32KB
  __shared__ bf16 ldsV[2][256 * 64];  // 2 x 32KB
  __shared__ bf16 ldsP[8][16 * 40];   // 10KB, 80B rows (16B-aligned)

  const int id = blockIdx.x;
  // XCD-aware swizzle: batch b pinned to XCDs {2b,2b+1} so K+V (4MB) stays L2-resident.
  const int xcd = id & 7;
  const int b = xcd >> 1;
  const int qt = (id >> 3) + ((xcd & 1) << 5);  // 0..63

  const bf16* Qb = Q + (size_t)b * S_LEN * 256;
  const bf16* Kb = K + (size_t)b * S_LEN * 256;
  const bf16* Vb = Vt + (size_t)b * 256 * S_LEN;
  bf16* Ob = O + (size_t)b * S_LEN * 256;

  const int t = threadIdx.x, w = t >> 6, l = t & 63, lm = l & 15, q = l >> 4;
  const int qg = w & 3, hf = w >> 2;
  const float CL2 = 0.09016844005556021f;  // log2(e)/sqrt(D) = log2(e)/16

  // staging offsets (elements); LDS slot s holds global chunk s^(row&7)
  int i8[4], gk[4], gv[4];
#pragma unroll
  for (int c = 0; c < 4; ++c) {
    int i = c * 512 + t;
    i8[c] = i * 8;
    int n = i >> 5, c8 = (i & 31) ^ (n & 7);
    gk[c] = n * 256 + c8 * 8;
    int d = i >> 3, c82 = (i & 7) ^ (d & 7);
    gv[c] = d * S_LEN + c82 * 8;
  }
  // K fragment base offsets (jt=0, cur=0); +4096*jt, +16384*cur are literals
  int koff[8];
#pragma unroll
  for (int ks = 0; ks < 8; ++ks)
    koff[ks] = hf * 8192 + lm * 256 + ((((ks << 2) + q) ^ (lm & 7)) << 3);
  // V fragment base offset (nt=0, cur=0); +1024*nt, +16384*cur are literals
  const int vbase = lm * 64 + ((((hf << 2) + q) ^ (lm & 7)) << 3);
  // P strip (per-wave private)
  bf16* pstrip = &ldsP[w][0];
  const int prd = lm * 40 + q * 8;

  // Q fragments persistent in registers: rows qt*64 + qg*16 + lm, all 256 k.
  bf16x8 qf[8];
  {
    const bf16* qrow = Qb + (size_t)(qt * 64 + qg * 16 + lm) * 256;
#pragma unroll
    for (int ks = 0; ks < 8; ++ks) qf[ks] = *(const bf16x8*)(qrow + ks * 32 + q * 8);
  }
  bf16x8 ones;
#pragma unroll
  for (int i = 0; i < 8; ++i) ones[i] = (bf16)1.0f;

  f32x4 o_acc[16] = {};
  f32x4 lsum = {0.f, 0.f, 0.f, 0.f};

  // stage tile 0 into buffer 0
#pragma unroll
  for (int c = 0; c < 4; ++c) {
    async16(&ldsK[0][0] + i8[c], Kb + gk[c]);
    async16(&ldsV[0][0] + i8[c], Vb + gv[c]);
  }

#pragma unroll 1
  for (int jj = 0; jj < 32; ++jj) {
#pragma unroll
    for (int half = 0; half < 2; ++half) {
      const int j = jj * 2 + half;  // half == buffer index (literal after unroll)
      __syncthreads();              // stage(j) drained; compute(j-1) done everywhere
      if (j + 1 < 64) {
        const bf16* kg = Kb + (size_t)(j + 1) * 16384;
        const bf16* vg = Vb + (size_t)(j + 1) * 64;
        bf16* dK = &ldsK[half ^ 1][0];
        bf16* dV = &ldsV[half ^ 1][0];
#pragma unroll
        for (int c = 0; c < 4; ++c) {
          async16(dK + i8[c], kg + gk[c]);
          async16(dV + i8[c], vg + gv[c]);
        }
      }

      // S = Q K^T over this wave's 32 KV columns
      const bf16* kbase = &ldsK[half][0];
      const bf16* vbase2 = &ldsV[half][0];
      f32x4 sv[2];
#pragma unroll
      for (int jt = 0; jt < 2; ++jt) {
        f32x4 s = {0.f, 0.f, 0.f, 0.f};
#pragma unroll
        for (int ks = 0; ks < 8; ++ks) {
          bf16x8 kf = *(const bf16x8*)(kbase + jt * 4096 + koff[ks]);
          s = mfma16(qf[ks], kf, s);
        }
        sv[jt] = s;
      }

      // P = exp2(S*CL2)  (no max subtraction), C-layout -> LDS -> A-layout
#pragma unroll
      for (int jt = 0; jt < 2; ++jt)
#pragma unroll
        for (int r = 0; r < 4; ++r)
          pstrip[(q * 4 + r) * 40 + jt * 16 + lm] =
              (bf16)__builtin_amdgcn_exp2f(sv[jt][r] * CL2);
      bf16x8 pa = *(const bf16x8*)(pstrip + prd);

      // l += row-sums of P via ones-column MFMA
      lsum = mfma16(pa, ones, lsum);

      // O += P @ V over this wave's 32 KV rows (full D)
#pragma unroll
      for (int nt = 0; nt < 16; ++nt) {
        bf16x8 vf = *(const bf16x8*)(vbase2 + nt * 1024 + vbase);
        o_acc[nt] = mfma16(pa, vf, o_acc[nt]);
      }
    }
  }

  // ---- merge the two KV-half states per Q-group (plain adds; no max) ----
  __syncthreads();
  float* mlbuf = (float*)&ldsP[0][0];  // [hf][qg][16] = 512B
  if (lm == 0) {
#pragma unroll
    for (int r = 0; r < 4; ++r) mlbuf[(hf * 4 + qg) * 16 + q * 4 + r] = lsum[r];
  }
  __syncthreads();
  float inv_l[4];
#pragma unroll
  for (int r = 0; r < 4; ++r)
    inv_l[r] = 1.0f / (lsum[r] + mlbuf[((1 - hf) * 4 + qg) * 16 + q * 4 + r]);

  float* obuf = (float*)&ldsK[0][0];  // [qg][nt][lane] f32x4 = 64KB
  if (hf == 1) {
#pragma unroll
    for (int nt = 0; nt < 16; ++nt)
      *(f32x4*)&obuf[(((qg << 4) | nt) * 64 + l) * 4] = o_acc[nt];
  }
  __syncthreads();
  if (hf == 0) {
    bf16* orow = Ob + (size_t)(qt * 64 + qg * 16) * 256;
#pragma unroll
    for (int nt = 0; nt < 16; ++nt) {
      f32x4 oo = *(const f32x4*)&obuf[(((qg << 4) | nt) * 64 + l) * 4];
#pragma unroll
      for (int r = 0; r < 4; ++r)
        orow[(size_t)(q * 4 + r) * 256 + nt * 16 + lm] =
            (bf16)((o_acc[nt][r] + oo[r]) * inv_l[r]);
    }
  }
}

// ---------------- gate: mean over S then dot Wg + sigmoid ----------------
__global__ __launch_bounds__(256) void gate_partial(const bf16* __restrict__ h,
                                                    float* __restrict__ part) {
  int bb = blockIdx.y;
  const bf16* hb = h + (size_t)bb * S_LEN * 256 + (size_t)blockIdx.x * 64 * 256;
  int t = threadIdx.x;
  float acc = 0.f;
#pragma unroll 4
  for (int s = 0; s < 64; ++s) acc += (float)hb[s * 256 + t];
  part[((size_t)bb * 64 + blockIdx.x) * 256 + t] = acc;
}

__global__ __launch_bounds__(256) void gate_final(const float* __restrict__ part,
                                                  const float* __restrict__ Wg,
                                                  const float* __restrict__ bg,
                                                  float* __restrict__ pg) {
  int bb = blockIdx.x, t = threadIdx.x;
  const float* p = part + (size_t)bb * 64 * 256;
  float acc = 0.f;
#pragma unroll 4
  for (int c = 0; c < 64; ++c) acc += p[c * 256 + t];
  acc *= Wg[t] * (1.0f / 4096.0f);
  __shared__ float red[256];
  red[t] = acc;
  __syncthreads();
  if (t < 64) {
    float a = red[t] + red[t + 64] + red[t + 128] + red[t + 192];
#pragma unroll
    for (int d = 1; d < 64; d <<= 1) a += __shfl_xor(a, d, 64);
    if (t == 0) pg[bb] = 1.0f / (1.0f + __expf(-(a + bg[0])));
  }
}

// ---------------- fused reparam + ELU + residual + LayerNorm ----------------
__global__ __launch_bounds__(64) void epilogue_kernel(const float* __restrict__ x,
                                                      const float* __restrict__ eps,
                                                      const float* __restrict__ mu,
                                                      const float* __restrict__ lv,
                                                      const float* __restrict__ gamma,
                                                      const float* __restrict__ beta,
                                                      float* __restrict__ out) {
  size_t base = (size_t)blockIdx.x * 256;
  int l = threadIdx.x;
  f32x4 xv = ((const f32x4*)(x + base))[l];
  f32x4 ev = ((const f32x4*)(eps + base))[l];
  f32x4 mv = ((const f32x4*)(mu + base))[l];
  f32x4 vv = ((const f32x4*)(lv + base))[l];
  f32x4 y;
  float s = 0.f, s2 = 0.f;
#pragma unroll
  for (int c = 0; c < 4; ++c) {
    float z = mv[c] + ev[c] * __expf(0.5f * vv[c]);
    z = z > 0.f ? z : (__expf(z) - 1.f);
    float yy = xv[c] + z;
    y[c] = yy;
    s += yy;
    s2 += yy * yy;
  }
#pragma unroll
  for (int d = 1; d < 64; d <<= 1) {
    s += __shfl_xor(s, d, 64);
    s2 += __shfl_xor(s2, d, 64);
  }
  float mean = s * (1.f / 256.f);
  float var = s2 * (1.f / 256.f) - mean * mean;
  float rstd = rsqrtf(var + 1e-5f);
  f32x4 gv = ((const f32x4*)gamma)[l];
  f32x4 bv = ((const f32x4*)beta)[l];
  f32x4 o;
#pragma unroll
  for (int c = 0; c < 4; ++c) o[c] = (y[c] - mean) * rstd * gv[c] + bv[c];
  ((f32x4*)(out + base))[l] = o;
}

// ---------------- launch ----------------
extern "C" void kernel_launch(void* const* d_in, const int* in_sizes, int n_in, void* d_out,
                              int out_size, void* d_ws, size_t ws_size, hipStream_t stream) {
  const float* x = (const float*)d_in[0];
  const float* eps = (const float*)d_in[1];
  const float* Wg = (const float*)d_in[18];
  const float* bg = (const float*)d_in[19];
  const float* gamma = (const float*)d_in[20];
  const float* beta = (const float*)d_in[21];

  char* ws = (char*)d_ws;
  bf16* x16 = (bf16*)(ws);                  // 8 MB
  bf16* q16 = (bf16*)(ws + 8388608);        // 8 MB
  bf16* k16 = (bf16*)(ws + 16777216);       // 8 MB
  bf16* v16 = (bf16*)(ws + 25165824);       // 8 MB
  bf16* vt16 = (bf16*)(ws + 33554432);      // 8 MB
  bf16* h16 = (bf16*)(ws + 41943040);       // 8 MB
  bf16* w16 = (bf16*)(ws + 50331648);       // 1 MB (8 x 256x256 bf16)
  float* gpart = (float*)(ws + 51380224);   // 256 KB

  float* out = (float*)d_out;
  float* mu = out + 4194304;
  float* lv = out + 8388608;
  float* pg = out + 12582912;

  cast_x_kernel<<<4096, 256, 0, stream>>>((const f32x4*)x, (ushort4*)x16, 1048576);
  WPtrs wp;
  for (int i = 0; i < 8; ++i) wp.p[i] = (const float*)d_in[2 + i];
  cast_w_kernel<<<dim3(64, 8), 256, 0, stream>>>(wp, (ushort4*)w16);

  GemmIO io1;
  io1.bias[0] = (const float*)d_in[10];
  io1.bias[1] = (const float*)d_in[11];
  io1.bias[2] = (const float*)d_in[12];
  io1.out[0] = q16; io1.out[1] = k16; io1.out[2] = v16;
  gemm_kernel<bf16><<<dim3(128, 2, 3), 256, 0, stream>>>(x16, w16, io1);
  transpose_kernel<<<dim3(64, 4, 4), 256, 0, stream>>>(v16, vt16);
  flash_kernel<<<256, 512, 0, stream>>>(q16, k16, vt16, h16);

  GemmIO io2;
  io2.bias[0] = (const float*)d_in[13];
  io2.bias[1] = (const float*)d_in[14];
  io2.bias[2] = (const float*)d_in[15];
  io2.out[0] = q16; io2.out[1] = k16; io2.out[2] = v16;
  gemm_kernel<bf16><<<dim3(128, 2, 3), 256, 0, stream>>>(h16, w16 + 3 * 65536, io2);
  transpose_kernel<<<dim3(64, 4, 4), 256, 0, stream>>>(v16, vt16);
  flash_kernel<<<256, 512, 0, stream>>>(q16, k16, vt16, h16);

  GemmIO io3;
  io3.bias[0] = (const float*)d_in[16];
  io3.bias[1] = (const float*)d_in[17];
  io3.bias[2] = nullptr;
  io3.out[0] = mu; io3.out[1] = lv; io3.out[2] = nullptr;
  gemm_kernel<float><<<dim3(128, 2, 2), 256, 0, stream>>>(h16, w16 + 6 * 65536, io3);

  gate_partial<<<dim3(64, 4), 256, 0, stream>>>(h16, gpart);
  gate_final<<<4, 256, 0, stream>>>(gpart, Wg, bg, pg);
  epilogue_kernel<<<16384, 64, 0, stream>>>(x, eps, mu, lv, gamma, beta, out);
}

// Round 5
// 375.009 us; speedup vs baseline: 2.2433x; 1.1490x over previous
//
#include <hip/hip_runtime.h>
#include <hip/hip_bf16.h>
#include <cstdint>
#include <cstddef>

// Problem: B=4, S=4096, D=256 two-layer full attention + VAE head. fp32 I/O.
// Strategy: bf16 MFMA everywhere GEMM-shaped; fp32 softmax/epilogue.

#define S_LEN 4096
#define DMODEL 256
#define NBATCH 4
#define MTOT (NBATCH * S_LEN)  // 16384

typedef __bf16 bf16;
typedef __bf16 bf16x8 __attribute__((ext_vector_type(8)));
typedef float f32x4 __attribute__((ext_vector_type(4)));
typedef float f32x16 __attribute__((ext_vector_type(16)));

__device__ __forceinline__ f32x4 mfma16(bf16x8 a, bf16x8 b, f32x4 c) {
  return __builtin_amdgcn_mfma_f32_16x16x32_bf16(a, b, c, 0, 0, 0);
}
__device__ __forceinline__ f32x16 mfma32(bf16x8 a, bf16x8 b, f32x16 c) {
  return __builtin_amdgcn_mfma_f32_32x32x16_bf16(a, b, c, 0, 0, 0);
}

// Async global->LDS, 16B per lane. LDS dest semantics: wave-uniform base + lane*16.
__device__ __forceinline__ void async16(bf16* lds, const bf16* g) {
  __builtin_amdgcn_global_load_lds(
      (const __attribute__((address_space(1))) unsigned int*)g,
      (__attribute__((address_space(3))) unsigned int*)lds, 16, 0, 0);
}

__device__ __forceinline__ unsigned short f2bfbits(float f) {
  return __builtin_bit_cast(unsigned short, (bf16)f);
}

// ---------------- cast kernels ----------------
__global__ void cast_x_kernel(const f32x4* __restrict__ src, ushort4* __restrict__ dst, int n4) {
  int i = blockIdx.x * 256 + threadIdx.x;
  if (i >= n4) return;
  f32x4 v = src[i];
  ushort4 o;
  o.x = f2bfbits(v[0]); o.y = f2bfbits(v[1]); o.z = f2bfbits(v[2]); o.w = f2bfbits(v[3]);
  dst[i] = o;
}

struct WPtrs { const float* p[8]; };

__global__ void cast_w_kernel(WPtrs wp, ushort4* __restrict__ dst) {
  int m = blockIdx.y;
  const f32x4* s = (const f32x4*)wp.p[m];
  int i = blockIdx.x * 256 + threadIdx.x;  // 0..16383
  f32x4 v = s[i];
  ushort4 o;
  o.x = f2bfbits(v[0]); o.y = f2bfbits(v[1]); o.z = f2bfbits(v[2]); o.w = f2bfbits(v[3]);
  dst[(size_t)m * 16384 + i] = o;
}

// ---------------- GEMM: out[m][n] = sum_k A[m][k]*W[n][k] + bias[n] ----------------
struct GemmIO {
  const float* bias[3];
  void* out[3];
};

template <typename OutT>
__global__ __launch_bounds__(256, 3) void gemm_kernel(const bf16* __restrict__ A,
                                                      const bf16* __restrict__ Wb, GemmIO io) {
  __shared__ bf16 ldsA[128 * 64];
  __shared__ bf16 ldsB[128 * 64];
  const int t = threadIdx.x;
  const int m0 = blockIdx.x * 128;
  const int n0 = blockIdx.y * 128;
  const bf16* W = Wb + (size_t)blockIdx.z * 65536;
  const int w = t >> 6, l = t & 63, lm = l & 15, q = l >> 4;
  const int wr = (w >> 1) * 64, wc = (w & 1) * 64;

  f32x4 acc[4][4] = {};
#pragma unroll 1
  for (int it = 0; it < 4; ++it) {
    const int k0 = it * 64;
#pragma unroll
    for (int c = 0; c < 4; ++c) {
      int i = c * 256 + t;
      int r = i >> 3, c8 = (i & 7) ^ (r & 7);
      async16(&ldsA[i * 8], A + (size_t)(m0 + r) * 256 + k0 + c8 * 8);
    }
#pragma unroll
    for (int c = 0; c < 4; ++c) {
      int i = c * 256 + t;
      int r = i >> 3, c8 = (i & 7) ^ (r & 7);
      async16(&ldsB[i * 8], W + (size_t)(n0 + r) * 256 + k0 + c8 * 8);
    }
    __syncthreads();
#pragma unroll
    for (int ks = 0; ks < 2; ++ks) {
      bf16x8 af[4], bfr[4];
#pragma unroll
      for (int i = 0; i < 4; ++i) {
        int ra = wr + i * 16 + lm;
        af[i] = *(const bf16x8*)&ldsA[ra * 64 + ((((ks << 2) + q) ^ (ra & 7)) << 3)];
        int rb = wc + i * 16 + lm;
        bfr[i] = *(const bf16x8*)&ldsB[rb * 64 + ((((ks << 2) + q) ^ (rb & 7)) << 3)];
      }
#pragma unroll
      for (int i = 0; i < 4; ++i)
#pragma unroll
        for (int jj = 0; jj < 4; ++jj) acc[i][jj] = mfma16(af[i], bfr[jj], acc[i][jj]);
    }
    __syncthreads();
  }
  const float* bias = io.bias[blockIdx.z];
  OutT* out = (OutT*)io.out[blockIdx.z];
#pragma unroll
  for (int jj = 0; jj < 4; ++jj) {
    int col = n0 + wc + jj * 16 + lm;
    float bv = bias[col];
#pragma unroll
    for (int i = 0; i < 4; ++i) {
      int row = m0 + wr + i * 16 + q * 4;
#pragma unroll
      for (int r = 0; r < 4; ++r)
        out[(size_t)(row + r) * 256 + col] = (OutT)(acc[i][jj][r] + bv);
    }
  }
}

// ---------------- transpose: V [B][S][256] -> Vt [B][256][S] ----------------
__global__ void transpose_kernel(const bf16* __restrict__ src, bf16* __restrict__ dst) {
  __shared__ bf16 tile[64][72];
  int s0 = blockIdx.x * 64, d0 = blockIdx.y * 64;
  size_t boff = (size_t)blockIdx.z * S_LEN * 256;
  size_t boffT = (size_t)blockIdx.z * 256 * S_LEN;
  int t = threadIdx.x;
#pragma unroll
  for (int rep = 0; rep < 16; ++rep) {
    int lin = rep * 256 + t;
    int r = lin >> 6, c = lin & 63;
    tile[r][c] = src[boff + (size_t)(s0 + r) * 256 + d0 + c];
  }
  __syncthreads();
#pragma unroll
  for (int rep = 0; rep < 16; ++rep) {
    int lin = rep * 256 + t;
    int r = lin >> 6, c = lin & 63;
    dst[boffT + (size_t)(d0 + r) * S_LEN + s0 + c] = tile[c][r];
  }
}

// ---------------- flash attention v4: 32x32x16 MFMA, no-merge wave layout ----------
// 256 blocks (1/CU), 512 threads = 8 waves = 2/SIMD. BM=64 Q rows, KV tile 128.
// Wave (qg = w&1, sub = w>>1):
//  QK phase: sub = KV quarter. S-strip 32x32 (rows qg*32+, cols sub*32+), K=256.
//            P = exp2(S*CL2) -> LDS strip [qg][sub][32][40] (no max: scores O(1)).
//  PV phase: sub = D quarter. Reads ALL 4 P strips of qg (k = 0..127) and V cols
//            sub*64..+63 -> disjoint 32x64 output per wave: NO merge, full l/wave.
// Single K (64KB) / V (64KB) buffers pipelined on the 2 barriers:
//  stageV(j) issued after B1 (V free) overlaps QK(j); stageK(j+1) after B2 overlaps PV(j).
// 32x32x16 layouts: A[m=lane&31][k=(lane>>5)*8+j]; B[k][n]: n=lane&31, k=(lane>>5)*8+j;
// C/D: col=lane&31, row=(reg&3)+8*(reg>>2)+4*(lane>>5)  [measured m74/m101].
__global__ __launch_bounds__(512, 2) void flash_kernel(const bf16* __restrict__ Q,
                                                       const bf16* __restrict__ K,
                                                       const bf16* __restrict__ Vt,
                                                       bf16* __restrict__ O) {
  __shared__ bf16 ldsK[128 * 256];  // 64KB: 128 kv-rows x 256 d, 32 chunks/row, ^(row&31)
  __shared__ bf16 ldsV[256 * 128];  // 64KB: 256 d-rows x 128 kv, 16 chunks/row, ^(d&15)
  __shared__ bf16 ldsP[8 * 1280];   // 20KB: [qg*4+hs][32][40]

  const int id = blockIdx.x;
  const int xcd = id & 7;
  const int b = xcd >> 1;
  const int qt = (id >> 3) + ((xcd & 1) << 5);  // 0..63

  const bf16* Qb = Q + (size_t)b * S_LEN * 256;
  const bf16* Kb = K + (size_t)b * S_LEN * 256;
  const bf16* Vb = Vt + (size_t)b * 256 * S_LEN;
  bf16* Ob = O + (size_t)b * S_LEN * 256;

  const int t = threadIdx.x, w = t >> 6, lane = t & 63;
  const int m31 = lane & 31, kh = lane >> 5;
  const int qg = w & 1, sub = w >> 1;
  const float CL2 = 0.09016844005556021f;  // log2(e)/sqrt(D) = log2(e)/16

  // staging offsets: 4096 16B-chunks per tile, 8 per thread
  int sld[8], skg[8], svg[8];
#pragma unroll
  for (int it = 0; it < 8; ++it) {
    int c = it * 512 + t;
    sld[it] = c * 8;
    int kr = c >> 5;
    skg[it] = kr * 256 + (((c & 31) ^ (kr & 31)) << 3);
    int d = c >> 4;
    svg[it] = d * S_LEN + (((c & 15) ^ (d & 15)) << 3);
  }
  // K B-frag offsets (j-invariant): n = sub*32 + m31, chunk = ks*2+kh, slot = chunk^(n&31)
  int koff[16];
  {
    const int n = sub * 32 + m31;
#pragma unroll
    for (int ks = 0; ks < 16; ++ks) koff[ks] = n * 256 + (((ks * 2 + kh) ^ (n & 31)) << 3);
  }
  // V B-frag offsets: d = (sub*2+nt2)*32 + m31, chunk = ks*2+kh, slot = chunk^(d&15)
  int voff[2][8];
#pragma unroll
  for (int nt2 = 0; nt2 < 2; ++nt2) {
    const int d = (sub * 2 + nt2) * 32 + m31;
#pragma unroll
    for (int ks = 0; ks < 8; ++ks) voff[nt2][ks] = d * 128 + (((ks * 2 + kh) ^ (d & 15)) << 3);
  }
  // P A-frag offsets: k = ks*16 + kh*8 -> strip hs = k>>5, col k&31
  int poff[8];
#pragma unroll
  for (int ks = 0; ks < 8; ++ks) {
    int kloc = ks * 16 + kh * 8;
    poff[ks] = (qg * 4 + (kloc >> 5)) * 1280 + m31 * 40 + (kloc & 31);
  }
  // P store base: strip (qg,sub), row offset 4*kh, col m31
  bf16* ps = &ldsP[(qg * 4 + sub) * 1280 + (kh * 4) * 40 + m31];

  // Q A-frags persistent: rows qt*64 + qg*32 + m31, k = ks*16 + kh*8 + i
  bf16x8 qf[16];
  {
    const bf16* qrow = Qb + (size_t)(qt * 64 + qg * 32 + m31) * 256 + kh * 8;
#pragma unroll
    for (int ks = 0; ks < 16; ++ks) qf[ks] = *(const bf16x8*)(qrow + ks * 16);
  }

  f32x16 o_acc[2] = {};
  float l_acc = 0.f;

  // prologue: stage K(0)
#pragma unroll
  for (int it = 0; it < 8; ++it) async16(&ldsK[0] + sld[it], Kb + skg[it]);

#pragma unroll 1
  for (int j = 0; j < 32; ++j) {
    __syncthreads();  // B1: stageK(j) drained; PV(j-1) done (V + P strips free)
    {                 // stage V(j), overlaps QK(j)
      const bf16* vg = Vb + j * 128;
#pragma unroll
      for (int it = 0; it < 8; ++it) async16(&ldsV[0] + sld[it], vg + svg[it]);
    }
    // QK(j): 32x32 S-strip, K=256
    f32x16 s = {};
#pragma unroll
    for (int ks = 0; ks < 16; ++ks) {
      bf16x8 kf = *(const bf16x8*)(&ldsK[0] + koff[ks]);
      s = mfma32(qf[ks], kf, s);
    }
    // P = exp2(S*CL2) -> strip (C-layout rows)
#pragma unroll
    for (int reg = 0; reg < 16; ++reg) {
      const int row = (reg & 3) + 8 * (reg >> 2);
      ps[row * 40] = (bf16)__builtin_amdgcn_exp2f(s[reg] * CL2);
    }
    __syncthreads();  // B2: stageV(j) drained; QK(j) done (K free); P visible
    if (j + 1 < 32) {  // stage K(j+1), overlaps PV(j)
      const bf16* kg = Kb + (size_t)(j + 1) * (128 * 256);
#pragma unroll
      for (int it = 0; it < 8; ++it) async16(&ldsK[0] + sld[it], kg + skg[it]);
    }
    // PV(j): rows qg*32+, cols sub*64..+63, k = full 128 kv
    bf16x8 pa[8];
#pragma unroll
    for (int ks = 0; ks < 8; ++ks) pa[ks] = *(const bf16x8*)(&ldsP[0] + poff[ks]);
#pragma unroll
    for (int ks = 0; ks < 8; ++ks)
#pragma unroll
      for (int i = 0; i < 8; ++i) l_acc += (float)pa[ks][i];
#pragma unroll
    for (int nt2 = 0; nt2 < 2; ++nt2)
#pragma unroll
      for (int ks = 0; ks < 8; ++ks) {
        bf16x8 vf = *(const bf16x8*)(&ldsV[0] + voff[nt2][ks]);
        o_acc[nt2] = mfma32(pa[ks], vf, o_acc[nt2]);
      }
  }

  // epilogue: fold kh halves of l, fetch per-row l via shfl, write disjoint 32x64 tile
  l_acc += __shfl_xor(l_acc, 32, 64);  // lanes now hold full l[m31]
  float linv[16];
#pragma unroll
  for (int reg = 0; reg < 16; ++reg) {
    const int row = (reg & 3) + 8 * (reg >> 2) + 4 * kh;
    linv[reg] = 1.0f / __shfl(l_acc, row, 64);
  }
  bf16* orow = Ob + (size_t)(qt * 64 + qg * 32) * 256 + sub * 64;
#pragma unroll
  for (int nt2 = 0; nt2 < 2; ++nt2)
#pragma unroll
    for (int reg = 0; reg < 16; ++reg) {
      const int row = (reg & 3) + 8 * (reg >> 2) + 4 * kh;
      orow[(size_t)row * 256 + nt2 * 32 + m31] = (bf16)(o_acc[nt2][reg] * linv[reg]);
    }
}

// ---------------- gate: mean over S then dot Wg + sigmoid ----------------
__global__ __launch_bounds__(256) void gate_partial(const bf16* __restrict__ h,
                                                    float* __restrict__ part) {
  int bb = blockIdx.y;
  const bf16* hb = h + (size_t)bb * S_LEN * 256 + (size_t)blockIdx.x * 64 * 256;
  int t = threadIdx.x;
  float acc = 0.f;
#pragma unroll 4
  for (int s = 0; s < 64; ++s) acc += (float)hb[s * 256 + t];
  part[((size_t)bb * 64 + blockIdx.x) * 256 + t] = acc;
}

__global__ __launch_bounds__(256) void gate_final(const float* __restrict__ part,
                                                  const float* __restrict__ Wg,
                                                  const float* __restrict__ bg,
                                                  float* __restrict__ pg) {
  int bb = blockIdx.x, t = threadIdx.x;
  const float* p = part + (size_t)bb * 64 * 256;
  float acc = 0.f;
#pragma unroll 4
  for (int c = 0; c < 64; ++c) acc += p[c * 256 + t];
  acc *= Wg[t] * (1.0f / 4096.0f);
  __shared__ float red[256];
  red[t] = acc;
  __syncthreads();
  if (t < 64) {
    float a = red[t] + red[t + 64] + red[t + 128] + red[t + 192];
#pragma unroll
    for (int d = 1; d < 64; d <<= 1) a += __shfl_xor(a, d, 64);
    if (t == 0) pg[bb] = 1.0f / (1.0f + __expf(-(a + bg[0])));
  }
}

// ---------------- fused reparam + ELU + residual + LayerNorm ----------------
__global__ __launch_bounds__(64) void epilogue_kernel(const float* __restrict__ x,
                                                      const float* __restrict__ eps,
                                                      const float* __restrict__ mu,
                                                      const float* __restrict__ lv,
                                                      const float* __restrict__ gamma,
                                                      const float* __restrict__ beta,
                                                      float* __restrict__ out) {
  size_t base = (size_t)blockIdx.x * 256;
  int l = threadIdx.x;
  f32x4 xv = ((const f32x4*)(x + base))[l];
  f32x4 ev = ((const f32x4*)(eps + base))[l];
  f32x4 mv = ((const f32x4*)(mu + base))[l];
  f32x4 vv = ((const f32x4*)(lv + base))[l];
  f32x4 y;
  float s = 0.f, s2 = 0.f;
#pragma unroll
  for (int c = 0; c < 4; ++c) {
    float z = mv[c] + ev[c] * __expf(0.5f * vv[c]);
    z = z > 0.f ? z : (__expf(z) - 1.f);
    float yy = xv[c] + z;
    y[c] = yy;
    s += yy;
    s2 += yy * yy;
  }
#pragma unroll
  for (int d = 1; d < 64; d <<= 1) {
    s += __shfl_xor(s, d, 64);
    s2 += __shfl_xor(s2, d, 64);
  }
  float mean = s * (1.f / 256.f);
  float var = s2 * (1.f / 256.f) - mean * mean;
  float rstd = rsqrtf(var + 1e-5f);
  f32x4 gv = ((const f32x4*)gamma)[l];
  f32x4 bv = ((const f32x4*)beta)[l];
  f32x4 o;
#pragma unroll
  for (int c = 0; c < 4; ++c) o[c] = (y[c] - mean) * rstd * gv[c] + bv[c];
  ((f32x4*)(out + base))[l] = o;
}

// ---------------- launch ----------------
extern "C" void kernel_launch(void* const* d_in, const int* in_sizes, int n_in, void* d_out,
                              int out_size, void* d_ws, size_t ws_size, hipStream_t stream) {
  const float* x = (const float*)d_in[0];
  const float* eps = (const float*)d_in[1];
  const float* Wg = (const float*)d_in[18];
  const float* bg = (const float*)d_in[19];
  const float* gamma = (const float*)d_in[20];
  const float* beta = (const float*)d_in[21];

  char* ws = (char*)d_ws;
  bf16* x16 = (bf16*)(ws);                  // 8 MB
  bf16* q16 = (bf16*)(ws + 8388608);        // 8 MB
  bf16* k16 = (bf16*)(ws + 16777216);       // 8 MB
  bf16* v16 = (bf16*)(ws + 25165824);       // 8 MB
  bf16* vt16 = (bf16*)(ws + 33554432);      // 8 MB
  bf16* h16 = (bf16*)(ws + 41943040);       // 8 MB
  bf16* w16 = (bf16*)(ws + 50331648);       // 1 MB (8 x 256x256 bf16)
  float* gpart = (float*)(ws + 51380224);   // 256 KB

  float* out = (float*)d_out;
  float* mu = out + 4194304;
  float* lv = out + 8388608;
  float* pg = out + 12582912;

  cast_x_kernel<<<4096, 256, 0, stream>>>((const f32x4*)x, (ushort4*)x16, 1048576);
  WPtrs wp;
  for (int i = 0; i < 8; ++i) wp.p[i] = (const float*)d_in[2 + i];
  cast_w_kernel<<<dim3(64, 8), 256, 0, stream>>>(wp, (ushort4*)w16);

  GemmIO io1;
  io1.bias[0] = (const float*)d_in[10];
  io1.bias[1] = (const float*)d_in[11];
  io1.bias[2] = (const float*)d_in[12];
  io1.out[0] = q16; io1.out[1] = k16; io1.out[2] = v16;
  gemm_kernel<bf16><<<dim3(128, 2, 3), 256, 0, stream>>>(x16, w16, io1);
  transpose_kernel<<<dim3(64, 4, 4), 256, 0, stream>>>(v16, vt16);
  flash_kernel<<<256, 512, 0, stream>>>(q16, k16, vt16, h16);

  GemmIO io2;
  io2.bias[0] = (const float*)d_in[13];
  io2.bias[1] = (const float*)d_in[14];
  io2.bias[2] = (const float*)d_in[15];
  io2.out[0] = q16; io2.out[1] = k16; io2.out[2] = v16;
  gemm_kernel<bf16><<<dim3(128, 2, 3), 256, 0, stream>>>(h16, w16 + 3 * 65536, io2);
  transpose_kernel<<<dim3(64, 4, 4), 256, 0, stream>>>(v16, vt16);
  flash_kernel<<<256, 512, 0, stream>>>(q16, k16, vt16, h16);

  GemmIO io3;
  io3.bias[0] = (const float*)d_in[16];
  io3.bias[1] = (const float*)d_in[17];
  io3.bias[2] = nullptr;
  io3.out[0] = mu; io3.out[1] = lv; io3.out[2] = nullptr;
  gemm_kernel<float><<<dim3(128, 2, 2), 256, 0, stream>>>(h16, w16 + 6 * 65536, io3);

  gate_partial<<<dim3(64, 4), 256, 0, stream>>>(h16, gpart);
  gate_final<<<4, 256, 0, stream>>>(gpart, Wg, bg, pg);
  epilogue_kernel<<<16384, 64, 0, stream>>>(x, eps, mu, lv, gamma, beta, out);
}